// Round 10
// baseline (4415.224 us; speedup 1.0000x reference)
//
#include <hip/hip_runtime.h>
#include <stdint.h>

typedef __attribute__((ext_vector_type(4))) float f32x4;
typedef _Float16 f16x8 __attribute__((ext_vector_type(8)));
typedef __attribute__((ext_vector_type(2))) unsigned int u32x2;
typedef unsigned short u16;
typedef unsigned int u32;

#define LSEQ 8192
#define BB 8
#define DD 1024
#define MM 65536      // B*L
#define NCH 128       // chunks per sequence (L/64)

__device__ __forceinline__ u16 f2h(float f) {
    _Float16 h = (_Float16)f;
    return *(u16*)&h;
}
__device__ __forceinline__ float h2f(u16 u) {
    _Float16 h = *(_Float16*)&u;
    return (float)h;
}

__device__ __forceinline__ void gload_lds16(const void* g, void* l) {
    __builtin_amdgcn_global_load_lds(
        (const __attribute__((address_space(1))) u32*)g,
        (__attribute__((address_space(3))) u32*)l, 16, 0, 0);
}

// ---------------- conv + silu + transpose -> xb f16 [B*L][D] ----------------
__global__ __launch_bounds__(256) void k_conv_silu(const float* __restrict__ x,
                                                   const float* __restrict__ w,
                                                   u16* __restrict__ xb) {
    int m = blockIdx.x;              // m = b*L + l
    int b = m >> 13, l = m & 8191;
    int d0 = threadIdx.x * 4;
    f32x4 wv[4];
#pragma unroll
    for (int j = 0; j < 4; j++) wv[j] = *(const f32x4*)&w[(d0 + j) * 4];
    float acc[4] = {0.f, 0.f, 0.f, 0.f};
#pragma unroll
    for (int kk = 0; kk < 4; kk++) {
        int lp = l - 3 + kk;
        if (lp >= 0) {
            f32x4 xv = *(const f32x4*)&x[((size_t)(lp * BB + b)) * DD + d0];
#pragma unroll
            for (int j = 0; j < 4; j++) acc[j] += xv[j] * wv[j][kk];
        }
    }
    u16 o[4];
#pragma unroll
    for (int j = 0; j < 4; j++) {
        float a = acc[j];
        o[j] = f2h(a / (1.f + __expf(-a)));
    }
    u32x2 pk;
    pk.x = (u32)o[0] | ((u32)o[1] << 16);
    pk.y = (u32)o[2] | ((u32)o[3] << 16);
    *(u32x2*)&xb[(size_t)m * DD + d0] = pk;
}

// ---------------- pack weights into B^T f16 layouts ----------------
__global__ __launch_bounds__(256) void k_packW(const float* __restrict__ Wq,
                                               const float* __restrict__ Wkg,
                                               const float* __restrict__ Wv,
                                               const float* __restrict__ Wg,
                                               const float* __restrict__ Wout,
                                               u16* __restrict__ Wcat,
                                               u16* __restrict__ WoutT) {
    int idx = blockIdx.x * 256 + threadIdx.x;
    const int T1 = 3072 * 1024;
    if (idx < T1) {
        int n = idx >> 10, kk = idx & 1023;
        float v;
        if (n < 512)        v = Wq [kk * 512 + n];
        else if (n < 1024)  v = Wkg[kk * 512 + (n - 512)];
        else if (n < 2048)  v = Wv [kk * 1024 + (n - 1024)];
        else                v = Wg [kk * 1024 + (n - 2048)];
        Wcat[idx] = f2h(v);
    } else {
        int j = idx - T1;
        if (j < 1024 * 1024) {
            int n = j >> 10, kk = j & 1023;
            WoutT[j] = f2h(Wout[kk * 1024 + n]);
        }
    }
}

// per-fragment epilogue (4 rows x 1 col-group of 16 handled by caller's lr)
template <int MODE>
__device__ __forceinline__ void epi_frag(f32x4 v, int grow0, int gcol,
                                         u16* __restrict__ qo, u16* __restrict__ gko,
                                         u16* __restrict__ ko, u16* __restrict__ vo,
                                         u16* __restrict__ sgo, const float* __restrict__ bg,
                                         float* __restrict__ out) {
#pragma unroll
    for (int rr = 0; rr < 4; rr++) {
        int grow = grow0 + rr;
        float val = v[rr];
        if (MODE == 1) {
            if (gcol < 512) {
                qo[(size_t)grow * 512 + gcol] = f2h(val);
            } else if (gcol < 1024) {
                float ls = fminf(val, 0.f) - log1pf(__expf(-fabsf(val)));
                float gkv = ls * 0.0625f;
                gko[(size_t)grow * 512 + (gcol - 512)] = f2h(gkv);
                ko [(size_t)grow * 512 + (gcol - 512)] = f2h(-expm1f(gkv));
            } else if (gcol < 2048) {
                vo[(size_t)grow * 1024 + (gcol - 1024)] = f2h(val);
            } else {
                float gg = val + bg[gcol - 2048];
                sgo[(size_t)grow * 1024 + (gcol - 2048)] = f2h(gg / (1.f + __expf(-gg)));
            }
        } else {
            int l = grow & 8191, b = grow >> 13;
            out[((size_t)(l * BB + b)) * DD + gcol] = val;
        }
    }
}

// ---------------- f16 GEMM, C = A[M][K] * Bt[N][K]^T, 256x256 tile, BK=64 ----------------
// 512 threads = 8 waves (2 M x 4 N); per-wave 128x64; double-buffered 128 KB LDS;
// T2 XOR-swizzle; 32 named f32x4 accumulators.
// R9 post-mortem: B-frag hoist across phases + default 128-VGPR allocator target
// -> spill (VGPR=128, WRITE 3.9GB). R10: per-phase B reload (12 transient
// ds_read_b128/phase, m201 pattern) + __launch_bounds__(512,2) (VGPR cap 256).
// Phase = {12 ds_reads; s_barrier; lgkmcnt(0); sched_barrier; setprio1;
// 16 MFMA; setprio0; s_barrier}. Staging burst+counted vmcnt (never 0 mid-loop).
template <int MODE>
__global__ __launch_bounds__(512, 2) void k_gemm_bt(
    const u16* __restrict__ A, const u16* __restrict__ Bt, int nt_tiles,
    u16* __restrict__ qo, u16* __restrict__ gko, u16* __restrict__ ko,
    u16* __restrict__ vo, u16* __restrict__ sgo, const float* __restrict__ bg,
    float* __restrict__ out) {
    const int K = 1024;
    __shared__ __align__(16) u16 Sm[65536];   // 128 KB: [2 buf][A 32KB | B 32KB]
    int tid = threadIdx.x;
    int w = tid >> 6, lane = tid & 63;
    int wm = w >> 2, wn = w & 3;
    int lr = lane & 15, lk = lane >> 4;

    // XCD-aware 2D-blocked tile mapping
    int xcd = blockIdx.x & 7;
    int cidx = blockIdx.x >> 3;
    int grpsz = nt_tiles * 4;
    int grp = cidx / grpsz;
    int r = cidx - grp * grpsz;
    int ntile = r >> 2;
    int mts_per_chunk = (gridDim.x >> 3) / nt_tiles;   // 32
    int mtile = xcd * mts_per_chunk + grp * 4 + (r & 3);
    int m0 = mtile << 8, n0 = ntile << 8;

#define DECL_ACC(MT) f32x4 a##MT##_0 = {0.f,0.f,0.f,0.f}, a##MT##_1 = {0.f,0.f,0.f,0.f}, \
                           a##MT##_2 = {0.f,0.f,0.f,0.f}, a##MT##_3 = {0.f,0.f,0.f,0.f};
    DECL_ACC(0) DECL_ACC(1) DECL_ACC(2) DECL_ACC(3)
    DECL_ACC(4) DECL_ACC(5) DECL_ACC(6) DECL_ACC(7)
#undef DECL_ACC

    // pre-swizzled global source: 16B slot (lane&7) ^ (row&7), row&7 = lane>>3
    int slot = (lane & 7) ^ ((lane >> 3) & 7);
    const u16* gA = A + (size_t)(m0 + w * 32 + (lane >> 3)) * K + slot * 8;
    const u16* gB = Bt + (size_t)(n0 + w * 32 + (lane >> 3)) * K + slot * 8;
    char* lA = (char*)Sm + w * 4096;            // + buf*65536 ; HW adds lane*16
    char* lB = (char*)Sm + 32768 + w * 4096;

#define STAGE(TT, OB) { \
    int k1 = (TT) << 6; \
    _Pragma("unroll") \
    for (int p = 0; p < 4; p++) { \
        gload_lds16(gA + (size_t)(p * 8) * K + k1, lA + (OB) + p * 1024); \
        gload_lds16(gB + (size_t)(p * 8) * K + k1, lB + (OB) + p * 1024); \
    } }

// one phase: 12 ds_reads (4 A, 8 B), barrier, lgkm-wait, 16 MFMA, barrier.
// All temps transient -> no cross-phase register pressure.
#define PHASE(As, Bs, MT0, MT1) { \
    int c0 = (lk ^ (lr & 7)) * 8; \
    int c1 = ((4 + lk) ^ (lr & 7)) * 8; \
    f16x8 yA0 = *(const f16x8*)&(As)[(wm * 128 + MT0 * 16 + lr) * 64 + c0]; \
    f16x8 yA1 = *(const f16x8*)&(As)[(wm * 128 + MT0 * 16 + lr) * 64 + c1]; \
    f16x8 yB0 = *(const f16x8*)&(As)[(wm * 128 + MT1 * 16 + lr) * 64 + c0]; \
    f16x8 yB1 = *(const f16x8*)&(As)[(wm * 128 + MT1 * 16 + lr) * 64 + c1]; \
    f16x8 b00 = *(const f16x8*)&(Bs)[(wn * 64 +  0 + lr) * 64 + c0]; \
    f16x8 b10 = *(const f16x8*)&(Bs)[(wn * 64 + 16 + lr) * 64 + c0]; \
    f16x8 b20 = *(const f16x8*)&(Bs)[(wn * 64 + 32 + lr) * 64 + c0]; \
    f16x8 b30 = *(const f16x8*)&(Bs)[(wn * 64 + 48 + lr) * 64 + c0]; \
    f16x8 b01 = *(const f16x8*)&(Bs)[(wn * 64 +  0 + lr) * 64 + c1]; \
    f16x8 b11 = *(const f16x8*)&(Bs)[(wn * 64 + 16 + lr) * 64 + c1]; \
    f16x8 b21 = *(const f16x8*)&(Bs)[(wn * 64 + 32 + lr) * 64 + c1]; \
    f16x8 b31 = *(const f16x8*)&(Bs)[(wn * 64 + 48 + lr) * 64 + c1]; \
    __builtin_amdgcn_s_barrier(); \
    asm volatile("s_waitcnt lgkmcnt(0)" ::: "memory"); \
    __builtin_amdgcn_sched_barrier(0); \
    __builtin_amdgcn_s_setprio(1); \
    a##MT0##_0 = __builtin_amdgcn_mfma_f32_16x16x32_f16(yA0, b00, a##MT0##_0, 0, 0, 0); \
    a##MT0##_1 = __builtin_amdgcn_mfma_f32_16x16x32_f16(yA0, b10, a##MT0##_1, 0, 0, 0); \
    a##MT0##_2 = __builtin_amdgcn_mfma_f32_16x16x32_f16(yA0, b20, a##MT0##_2, 0, 0, 0); \
    a##MT0##_3 = __builtin_amdgcn_mfma_f32_16x16x32_f16(yA0, b30, a##MT0##_3, 0, 0, 0); \
    a##MT1##_0 = __builtin_amdgcn_mfma_f32_16x16x32_f16(yB0, b00, a##MT1##_0, 0, 0, 0); \
    a##MT1##_1 = __builtin_amdgcn_mfma_f32_16x16x32_f16(yB0, b10, a##MT1##_1, 0, 0, 0); \
    a##MT1##_2 = __builtin_amdgcn_mfma_f32_16x16x32_f16(yB0, b20, a##MT1##_2, 0, 0, 0); \
    a##MT1##_3 = __builtin_amdgcn_mfma_f32_16x16x32_f16(yB0, b30, a##MT1##_3, 0, 0, 0); \
    a##MT0##_0 = __builtin_amdgcn_mfma_f32_16x16x32_f16(yA1, b01, a##MT0##_0, 0, 0, 0); \
    a##MT0##_1 = __builtin_amdgcn_mfma_f32_16x16x32_f16(yA1, b11, a##MT0##_1, 0, 0, 0); \
    a##MT0##_2 = __builtin_amdgcn_mfma_f32_16x16x32_f16(yA1, b21, a##MT0##_2, 0, 0, 0); \
    a##MT0##_3 = __builtin_amdgcn_mfma_f32_16x16x32_f16(yA1, b31, a##MT0##_3, 0, 0, 0); \
    a##MT1##_0 = __builtin_amdgcn_mfma_f32_16x16x32_f16(yB1, b01, a##MT1##_0, 0, 0, 0); \
    a##MT1##_1 = __builtin_amdgcn_mfma_f32_16x16x32_f16(yB1, b11, a##MT1##_1, 0, 0, 0); \
    a##MT1##_2 = __builtin_amdgcn_mfma_f32_16x16x32_f16(yB1, b21, a##MT1##_2, 0, 0, 0); \
    a##MT1##_3 = __builtin_amdgcn_mfma_f32_16x16x32_f16(yB1, b31, a##MT1##_3, 0, 0, 0); \
    __builtin_amdgcn_s_setprio(0); \
    __builtin_amdgcn_s_barrier(); }

#define KTILE(OB) { \
    const u16* As = Sm + (OB) / 2; \
    const u16* Bs = As + 16384; \
    PHASE(As, Bs, 0, 1) \
    PHASE(As, Bs, 2, 3) \
    PHASE(As, Bs, 4, 5) \
    PHASE(As, Bs, 6, 7) }

    // prologue: stage K-tiles 0 and 1 (16 loads in flight per thread)
    STAGE(0, 0)
    STAGE(1, 65536)

    for (int t = 0; t < 15; ++t) {
        // wait for stage(t); stage(t+1)'s 8 loads stay in flight
        asm volatile("s_waitcnt vmcnt(8)" ::: "memory");
        __builtin_amdgcn_sched_barrier(0);
        __builtin_amdgcn_s_barrier();   // all waves' tile-t writes landed
        if (t & 1) { KTILE(65536) } else { KTILE(0) }
        // buf(t&1) fully consumed (closing barrier of last phase)
        if (t < 14) {
            STAGE(t + 2, (t & 1) * 65536)
        }
    }
    // tile 15 (buf 1): everything must be in
    asm volatile("s_waitcnt vmcnt(0)" ::: "memory");
    __builtin_amdgcn_sched_barrier(0);
    __builtin_amdgcn_s_barrier();
    KTILE(65536)

#undef KTILE
#undef PHASE
#undef STAGE

#define EPI_ROW(MT) { \
    int gr0 = m0 + wm * 128 + MT * 16 + lk * 4; \
    epi_frag<MODE>(a##MT##_0, gr0, n0 + wn * 64 +  0 + lr, qo, gko, ko, vo, sgo, bg, out); \
    epi_frag<MODE>(a##MT##_1, gr0, n0 + wn * 64 + 16 + lr, qo, gko, ko, vo, sgo, bg, out); \
    epi_frag<MODE>(a##MT##_2, gr0, n0 + wn * 64 + 32 + lr, qo, gko, ko, vo, sgo, bg, out); \
    epi_frag<MODE>(a##MT##_3, gr0, n0 + wn * 64 + 48 + lr, qo, gko, ko, vo, sgo, bg, out); }
    EPI_ROW(0) EPI_ROW(1) EPI_ROW(2) EPI_ROW(3)
    EPI_ROW(4) EPI_ROW(5) EPI_ROW(6) EPI_ROW(7)
#undef EPI_ROW
}

// ---------------- pass1: per-chunk increment M_c = sum_s k_s e^{G_C - G_s} v_s^T ----------------
__global__ __launch_bounds__(64) void k_pass1(const u16* __restrict__ gkb,
                                              const u16* __restrict__ kb,
                                              const u16* __restrict__ vb,
                                              float* __restrict__ Mo,
                                              float* __restrict__ eGC) {
    __shared__ __align__(16) float kkT[64 * 32];  // [t][i] fp32
    int bhc = blockIdx.x;
    int c = bhc & 127, bh = bhc >> 7;
    int h = bh & 15, b = bh >> 4;
    int m0 = b * LSEQ + c * 64;
    int lane = threadIdx.x;
    if (lane < 32) {
        int i = lane;
        size_t base = (size_t)m0 * 512 + h * 32 + i;
        float G = 0.f;
        for (int t = 0; t < 64; t++) {
            G += h2f(gkb[base + (size_t)t * 512]);
            G = fmaxf(G, -60.f);
            kkT[t * 32 + i] = h2f(kb[base + (size_t)t * 512]) * __expf(-G);
        }
        eGC[bhc * 32 + i] = __expf(G);
    }
    __syncthreads();
    float Ma[32];
#pragma unroll
    for (int i = 0; i < 32; i++) Ma[i] = 0.f;
    size_t vbase = (size_t)m0 * 1024 + h * 64 + lane;
    for (int t = 0; t < 64; t++) {
        float vj = h2f(vb[vbase + (size_t)t * 1024]);
#pragma unroll
        for (int i4 = 0; i4 < 32; i4 += 4) {
            f32x4 kk4 = *(const f32x4*)&kkT[t * 32 + i4];
            Ma[i4 + 0] += kk4[0] * vj;
            Ma[i4 + 1] += kk4[1] * vj;
            Ma[i4 + 2] += kk4[2] * vj;
            Ma[i4 + 3] += kk4[3] * vj;
        }
    }
    size_t mb = (size_t)bhc * 2048 + lane;
#pragma unroll
    for (int i = 0; i < 32; i++) Mo[mb + i * 64] = Ma[i];
}

// ---------------- pass2: chunk-level recurrence (sequential over 128 chunks) ----------------
__global__ __launch_bounds__(64) void k_pass2(float* Mbuf, float* Sbuf,
                                              const float* __restrict__ eGC,
                                              float* __restrict__ state_out, int aliased) {
    int bh = blockIdx.x;
    int j = threadIdx.x;
    float S[32];
#pragma unroll
    for (int i = 0; i < 32; i++) S[i] = 0.f;
    for (int c = 0; c < NCH; c++) {
        size_t base = ((size_t)bh * NCH + c) * 2048;
        float mv[32], ev[32];
#pragma unroll
        for (int i = 0; i < 32; i++) mv[i] = Mbuf[base + i * 64 + j];
#pragma unroll
        for (int i = 0; i < 32; i++) ev[i] = eGC[(bh * NCH + c) * 32 + i];
        if (aliased) { asm volatile("s_waitcnt vmcnt(0)" ::: "memory"); }
#pragma unroll
        for (int i = 0; i < 32; i++) Sbuf[base + i * 64 + j] = S[i];  // chunk-START state
#pragma unroll
        for (int i = 0; i < 32; i++) S[i] = (S[i] + mv[i]) * ev[i];
    }
    size_t so = (size_t)bh * 2048 + j;
#pragma unroll
    for (int i = 0; i < 32; i++) state_out[so + i * 64] = S[i];
}

// ---------------- pass3: intra-chunk outputs + aug + groupnorm + silu-gate ----------------
__global__ __launch_bounds__(64) void k_pass3(const u16* __restrict__ qb,
                                              const u16* __restrict__ gkb,
                                              const u16* __restrict__ kb,
                                              const u16* __restrict__ vb,
                                              const u16* __restrict__ sgb,
                                              const float* __restrict__ Sbuf,
                                              const float* __restrict__ aug,
                                              u16* __restrict__ PRE) {
    __shared__ __align__(16) float qqT[64 * 32];  // [t][i] fp32
    __shared__ __align__(16) float kkT[64 * 32];
    __shared__ float awl[64];
    int bhc = blockIdx.x;
    int c = bhc & 127, bh = bhc >> 7;
    int h = bh & 15, b = bh >> 4;
    int m0 = b * LSEQ + c * 64;
    int lane = threadIdx.x;
    const float scale = 0.17677669529663689f;  // 1/sqrt(32)
    if (lane < 32) {
        int i = lane;
        float augi = aug[h * 32 + i];
        size_t base = (size_t)m0 * 512 + h * 32 + i;
        float G = 0.f;
        for (int t = 0; t < 64; t++) {
            float gkv = h2f(gkb[base + (size_t)t * 512]);
            float qv  = h2f(qb [base + (size_t)t * 512]);
            float kv  = h2f(kb [base + (size_t)t * 512]);
            G += gkv;
            G = fmaxf(G, -60.f);
            float en = __expf(-G);
            float ep = __expf(G);
            qqT[t * 32 + i] = qv * ep * scale;
            kkT[t * 32 + i] = kv * en;
            float p = qv * kv * augi;  // aug uses raw q,k
            p += __shfl_xor(p, 1);
            p += __shfl_xor(p, 2);
            p += __shfl_xor(p, 4);
            p += __shfl_xor(p, 8);
            p += __shfl_xor(p, 16);
            if (i == 0) awl[t] = p;
        }
    }
    __syncthreads();
    float T[32];
    size_t sb = (size_t)bhc * 2048 + lane;
#pragma unroll
    for (int i = 0; i < 32; i++) T[i] = Sbuf[sb + i * 64];
    size_t vbase = (size_t)m0 * 1024 + h * 64 + lane;
    for (int t = 0; t < 64; t++) {
        float vj  = h2f(vb [vbase + (size_t)t * 1024]);
        float sgj = h2f(sgb[vbase + (size_t)t * 1024]);
        float aw = awl[t];
        float o = 0.f;
#pragma unroll
        for (int i4 = 0; i4 < 32; i4 += 4) {
            f32x4 kk4 = *(const f32x4*)&kkT[t * 32 + i4];
            f32x4 qq4 = *(const f32x4*)&qqT[t * 32 + i4];
#pragma unroll
            for (int e = 0; e < 4; e++) {
                T[i4 + e] += kk4[e] * vj;    // T_t = S_c + sum kk v
                o += qq4[e] * T[i4 + e];     // o_t = qq_t . T_t
            }
        }
        o += 1.f / (1.f + __expf(-aw * vj));       // + sigmoid(aug_w * v)
        // group norm over dv=64 (all 64 lanes)
        float s1 = o, s2 = o * o;
#pragma unroll
        for (int msk = 1; msk < 64; msk <<= 1) {
            s1 += __shfl_xor(s1, msk);
            s2 += __shfl_xor(s2, msk);
        }
        float mu = s1 * 0.015625f;
        float var = s2 * 0.015625f - mu * mu;
        float on = (o - mu) * rsqrtf(fmaxf(var, 0.f) + 1e-5f);
        PRE[vbase + (size_t)t * 1024] = f2h(on * sgj);
    }
}

// ---------------- host launch ----------------
extern "C" void kernel_launch(void* const* d_in, const int* in_sizes, int n_in,
                              void* d_out, int out_size, void* d_ws, size_t ws_size,
                              hipStream_t stream) {
    (void)in_sizes; (void)n_in; (void)out_size;
    const float* x      = (const float*)d_in[0];
    const float* conv_w = (const float*)d_in[1];
    const float* Wq     = (const float*)d_in[2];
    const float* Wkg    = (const float*)d_in[3];
    const float* Wv     = (const float*)d_in[4];
    const float* Wg     = (const float*)d_in[5];
    const float* bg     = (const float*)d_in[6];
    const float* Wout   = (const float*)d_in[7];
    const float* aug    = (const float*)d_in[8];

    char* ws = (char*)d_ws;
    u16*   xb    = (u16*)  (ws + 0);            // 134217728 B (also PRE later)
    u16*   Wcat  = (u16*)  (ws + 134217728);    //   6291456
    u16*   WoutT = (u16*)  (ws + 140509184);    //   2097152
    u16*   qb    = (u16*)  (ws + 142606336);    //  67108864
    u16*   gkb   = (u16*)  (ws + 209715200);    //  67108864
    u16*   kbuf  = (u16*)  (ws + 276824064);    //  67108864
    u16*   sgb   = (u16*)  (ws + 343932928);    // 134217728
    float* Mbuf  = (float*)(ws + 478150656);    // 134217728
    float* eGC   = (float*)(ws + 612368384);    //   2097152
    float* Sb    = (float*)(ws + 614465536);    // 134217728 (optional)
    const size_t REQ_FULL = 748683264ull;
    int aliased = (ws_size < REQ_FULL) ? 1 : 0;
    float* Sbuf = aliased ? Mbuf : Sb;

    float* out = (float*)d_out;
    float* state_out = out + 67108864;
    u16* vb = (u16*)d_out;  // v (f16) lives in out region until GEMM2 overwrites it

    k_conv_silu<<<dim3(65536), dim3(256), 0, stream>>>(x, conv_w, xb);
    k_packW<<<dim3(16384), dim3(256), 0, stream>>>(Wq, Wkg, Wv, Wg, Wout, Wcat, WoutT);
    k_gemm_bt<1><<<dim3(3072), dim3(512), 0, stream>>>(xb, Wcat, 12,
                                                       qb, gkb, kbuf, vb, sgb, bg, nullptr);
    k_pass1<<<dim3(16384), dim3(64), 0, stream>>>(gkb, kbuf, vb, Mbuf, eGC);
    k_pass2<<<dim3(128), dim3(64), 0, stream>>>(Mbuf, Sbuf, eGC, state_out, aliased);
    k_pass3<<<dim3(16384), dim3(64), 0, stream>>>(qb, gkb, kbuf, vb, sgb, Sbuf, aug, xb /*PRE*/);
    k_gemm_bt<2><<<dim3(1024), dim3(512), 0, stream>>>(xb, WoutT, 4,
                                                       nullptr, nullptr, nullptr, nullptr, nullptr, nullptr, out);
}

// Round 11
// 2456.288 us; speedup vs baseline: 1.7975x; 1.7975x over previous
//
#include <hip/hip_runtime.h>
#include <stdint.h>

typedef __attribute__((ext_vector_type(4))) float f32x4;
typedef _Float16 f16x8 __attribute__((ext_vector_type(8)));
typedef __attribute__((ext_vector_type(2))) unsigned int u32x2;
typedef unsigned short u16;
typedef unsigned int u32;

#define LSEQ 8192
#define BB 8
#define DD 1024
#define MM 65536      // B*L
#define NCH 128       // chunks per sequence (L/64)

__device__ __forceinline__ u16 f2h(float f) {
    _Float16 h = (_Float16)f;
    return *(u16*)&h;
}
__device__ __forceinline__ float h2f(u16 u) {
    _Float16 h = *(_Float16*)&u;
    return (float)h;
}

__device__ __forceinline__ void gload_lds16(const void* g, void* l) {
    __builtin_amdgcn_global_load_lds(
        (const __attribute__((address_space(1))) u32*)g,
        (__attribute__((address_space(3))) u32*)l, 16, 0, 0);
}

// ---------------- conv + silu + transpose -> xb f16 [B*L][D] ----------------
__global__ __launch_bounds__(256) void k_conv_silu(const float* __restrict__ x,
                                                   const float* __restrict__ w,
                                                   u16* __restrict__ xb) {
    int m = blockIdx.x;              // m = b*L + l
    int b = m >> 13, l = m & 8191;
    int d0 = threadIdx.x * 4;
    f32x4 wv[4];
#pragma unroll
    for (int j = 0; j < 4; j++) wv[j] = *(const f32x4*)&w[(d0 + j) * 4];
    float acc[4] = {0.f, 0.f, 0.f, 0.f};
#pragma unroll
    for (int kk = 0; kk < 4; kk++) {
        int lp = l - 3 + kk;
        if (lp >= 0) {
            f32x4 xv = *(const f32x4*)&x[((size_t)(lp * BB + b)) * DD + d0];
#pragma unroll
            for (int j = 0; j < 4; j++) acc[j] += xv[j] * wv[j][kk];
        }
    }
    u16 o[4];
#pragma unroll
    for (int j = 0; j < 4; j++) {
        float a = acc[j];
        o[j] = f2h(a / (1.f + __expf(-a)));
    }
    u32x2 pk;
    pk.x = (u32)o[0] | ((u32)o[1] << 16);
    pk.y = (u32)o[2] | ((u32)o[3] << 16);
    *(u32x2*)&xb[(size_t)m * DD + d0] = pk;
}

// ---------------- pack weights into B^T f16 layouts ----------------
__global__ __launch_bounds__(256) void k_packW(const float* __restrict__ Wq,
                                               const float* __restrict__ Wkg,
                                               const float* __restrict__ Wv,
                                               const float* __restrict__ Wg,
                                               const float* __restrict__ Wout,
                                               u16* __restrict__ Wcat,
                                               u16* __restrict__ WoutT) {
    int idx = blockIdx.x * 256 + threadIdx.x;
    const int T1 = 3072 * 1024;
    if (idx < T1) {
        int n = idx >> 10, kk = idx & 1023;
        float v;
        if (n < 512)        v = Wq [kk * 512 + n];
        else if (n < 1024)  v = Wkg[kk * 512 + (n - 512)];
        else if (n < 2048)  v = Wv [kk * 1024 + (n - 1024)];
        else                v = Wg [kk * 1024 + (n - 2048)];
        Wcat[idx] = f2h(v);
    } else {
        int j = idx - T1;
        if (j < 1024 * 1024) {
            int n = j >> 10, kk = j & 1023;
            WoutT[j] = f2h(Wout[kk * 1024 + n]);
        }
    }
}

// ---------------- f16 GEMM, C = A[M][K] * Bt[N][K]^T, 128x128 tile ----------------
// R10 post-mortem: 256²+phase attempts spill at the allocator's 128-VGPR target;
// revert to the proven R4 128² structure (VGPR 96, no spill, conflicts 0) and fix
// its ONE diagnosed defect: L2 thrash (FETCH 1.55 GB) from m-partitioned XCDs
// sweeping the full 6 MB B. Now N-PARTITIONED XCD mapping: each XCD owns
// nt_tiles/8 n-tiles (GEMM1: 3 -> 768 KB B-slab; GEMM2: 1 -> 256 KB), B stays
// L2-resident; m sweeps inner (A-tile reused from L2 across its n-tiles).
// MODE 1: fused projection epilogue (q/gk/k/v/sg all f16)
// MODE 2: output GEMM with [B,L,D]->[L,B,D] scatter (fp32)
template <int MODE>
__global__ __launch_bounds__(256) void k_gemm_bt(
    const u16* __restrict__ A, const u16* __restrict__ Bt, int nt_tiles,
    u16* __restrict__ qo, u16* __restrict__ gko, u16* __restrict__ ko,
    u16* __restrict__ vo, u16* __restrict__ sgo, const float* __restrict__ bg,
    float* __restrict__ out) {
    const int K = 1024;
    __shared__ __align__(16) u16 As[128 * 64];
    __shared__ __align__(16) u16 Bs[128 * 64];
    int tid = threadIdx.x;
    // N-partitioned XCD mapping (blockIdx.x % 8 ~ XCD round-robin heuristic)
    int xcd = blockIdx.x & 7;
    int cidx = blockIdx.x >> 3;
    int ntpx = nt_tiles >> 3;               // n-tiles per XCD (3 or 1)
    int mt0 = cidx / ntpx;
    int nt0 = xcd * ntpx + (cidx - mt0 * ntpx);
    int m0 = mt0 << 7, n0 = nt0 << 7;
    int w = tid >> 6, lane = tid & 63;
    int wm = w >> 1, wn = w & 1;
    int lr = lane & 15, lk = lane >> 4;
    f32x4 acc[4][4];
#pragma unroll
    for (int i = 0; i < 4; i++)
#pragma unroll
        for (int j = 0; j < 4; j++) acc[i][j] = {0.f, 0.f, 0.f, 0.f};

    // pre-swizzled global source column: 16B slot (lane&7) ^ (row&7)
    int csw = (((tid & 7) ^ ((tid >> 3) & 7))) * 8;
    const u16* gA = A + (size_t)(m0 + (tid >> 3)) * K + csw;
    const u16* gB = Bt + (size_t)(n0 + (tid >> 3)) * K + csw;
    char* lA = (char*)As + w * 1024;   // wave-uniform LDS base (+ lane*16 by HW)
    char* lB = (char*)Bs + w * 1024;
    int xsw = (lr & 7) * 8;            // read-side XOR (elements)

    for (int k0 = 0; k0 < K; k0 += 64) {
#pragma unroll
        for (int p = 0; p < 4; p++) gload_lds16(gA + (size_t)(p * 32) * K + k0, lA + p * 4096);
#pragma unroll
        for (int p = 0; p < 4; p++) gload_lds16(gB + (size_t)(p * 32) * K + k0, lB + p * 4096);
        __syncthreads();
#pragma unroll
        for (int ks = 0; ks < 2; ks++) {
            f16x8 af[4], bfr[4];
#pragma unroll
            for (int mt = 0; mt < 4; mt++)
                af[mt] = *(const f16x8*)&As[(wm * 64 + mt * 16 + lr) * 64 + ((ks * 32 + lk * 8) ^ xsw)];
#pragma unroll
            for (int nt = 0; nt < 4; nt++)
                bfr[nt] = *(const f16x8*)&Bs[(wn * 64 + nt * 16 + lr) * 64 + ((ks * 32 + lk * 8) ^ xsw)];
#pragma unroll
            for (int mt = 0; mt < 4; mt++)
#pragma unroll
                for (int nt = 0; nt < 4; nt++)
                    acc[mt][nt] = __builtin_amdgcn_mfma_f32_16x16x32_f16(af[mt], bfr[nt], acc[mt][nt], 0, 0, 0);
        }
        __syncthreads();
    }

#pragma unroll
    for (int mt = 0; mt < 4; mt++) {
#pragma unroll
        for (int nt = 0; nt < 4; nt++) {
            int gcol = n0 + wn * 64 + nt * 16 + lr;
#pragma unroll
            for (int r = 0; r < 4; r++) {
                int grow = m0 + wm * 64 + mt * 16 + lk * 4 + r;
                float val = acc[mt][nt][r];
                if (MODE == 1) {
                    if (gcol < 512) {
                        qo[(size_t)grow * 512 + gcol] = f2h(val);
                    } else if (gcol < 1024) {
                        float ls = fminf(val, 0.f) - log1pf(__expf(-fabsf(val)));
                        float gkv = ls * 0.0625f;
                        gko[(size_t)grow * 512 + (gcol - 512)] = f2h(gkv);
                        ko [(size_t)grow * 512 + (gcol - 512)] = f2h(-expm1f(gkv));
                    } else if (gcol < 2048) {
                        vo[(size_t)grow * 1024 + (gcol - 1024)] = f2h(val);
                    } else {
                        float gg = val + bg[gcol - 2048];
                        sgo[(size_t)grow * 1024 + (gcol - 2048)] = f2h(gg / (1.f + __expf(-gg)));
                    }
                } else {
                    int l = grow & 8191, b = grow >> 13;
                    out[((size_t)(l * BB + b)) * DD + gcol] = val;
                }
            }
        }
    }
}

// ---------------- pass1: per-chunk increment M_c = sum_s k_s e^{G_C - G_s} v_s^T ----------------
__global__ __launch_bounds__(64) void k_pass1(const u16* __restrict__ gkb,
                                              const u16* __restrict__ kb,
                                              const u16* __restrict__ vb,
                                              float* __restrict__ Mo,
                                              float* __restrict__ eGC) {
    __shared__ __align__(16) float kkT[64 * 32];  // [t][i] fp32
    int bhc = blockIdx.x;
    int c = bhc & 127, bh = bhc >> 7;
    int h = bh & 15, b = bh >> 4;
    int m0 = b * LSEQ + c * 64;
    int lane = threadIdx.x;
    if (lane < 32) {
        int i = lane;
        size_t base = (size_t)m0 * 512 + h * 32 + i;
        float G = 0.f;
        for (int t = 0; t < 64; t++) {
            G += h2f(gkb[base + (size_t)t * 512]);
            G = fmaxf(G, -60.f);
            kkT[t * 32 + i] = h2f(kb[base + (size_t)t * 512]) * __expf(-G);
        }
        eGC[bhc * 32 + i] = __expf(G);
    }
    __syncthreads();
    float Ma[32];
#pragma unroll
    for (int i = 0; i < 32; i++) Ma[i] = 0.f;
    size_t vbase = (size_t)m0 * 1024 + h * 64 + lane;
    for (int t = 0; t < 64; t++) {
        float vj = h2f(vb[vbase + (size_t)t * 1024]);
#pragma unroll
        for (int i4 = 0; i4 < 32; i4 += 4) {
            f32x4 kk4 = *(const f32x4*)&kkT[t * 32 + i4];
            Ma[i4 + 0] += kk4[0] * vj;
            Ma[i4 + 1] += kk4[1] * vj;
            Ma[i4 + 2] += kk4[2] * vj;
            Ma[i4 + 3] += kk4[3] * vj;
        }
    }
    size_t mb = (size_t)bhc * 2048 + lane;
#pragma unroll
    for (int i = 0; i < 32; i++) Mo[mb + i * 64] = Ma[i];
}

// ---------------- pass2: chunk-level recurrence (sequential over 128 chunks) ----------------
__global__ __launch_bounds__(64) void k_pass2(float* Mbuf, float* Sbuf,
                                              const float* __restrict__ eGC,
                                              float* __restrict__ state_out, int aliased) {
    int bh = blockIdx.x;
    int j = threadIdx.x;
    float S[32];
#pragma unroll
    for (int i = 0; i < 32; i++) S[i] = 0.f;
    for (int c = 0; c < NCH; c++) {
        size_t base = ((size_t)bh * NCH + c) * 2048;
        float mv[32], ev[32];
#pragma unroll
        for (int i = 0; i < 32; i++) mv[i] = Mbuf[base + i * 64 + j];
#pragma unroll
        for (int i = 0; i < 32; i++) ev[i] = eGC[(bh * NCH + c) * 32 + i];
        if (aliased) { asm volatile("s_waitcnt vmcnt(0)" ::: "memory"); }
#pragma unroll
        for (int i = 0; i < 32; i++) Sbuf[base + i * 64 + j] = S[i];  // chunk-START state
#pragma unroll
        for (int i = 0; i < 32; i++) S[i] = (S[i] + mv[i]) * ev[i];
    }
    size_t so = (size_t)bh * 2048 + j;
#pragma unroll
    for (int i = 0; i < 32; i++) state_out[so + i * 64] = S[i];
}

// ---------------- pass3: intra-chunk outputs + aug + groupnorm + silu-gate ----------------
__global__ __launch_bounds__(64) void k_pass3(const u16* __restrict__ qb,
                                              const u16* __restrict__ gkb,
                                              const u16* __restrict__ kb,
                                              const u16* __restrict__ vb,
                                              const u16* __restrict__ sgb,
                                              const float* __restrict__ Sbuf,
                                              const float* __restrict__ aug,
                                              u16* __restrict__ PRE) {
    __shared__ __align__(16) float qqT[64 * 32];  // [t][i] fp32
    __shared__ __align__(16) float kkT[64 * 32];
    __shared__ float awl[64];
    int bhc = blockIdx.x;
    int c = bhc & 127, bh = bhc >> 7;
    int h = bh & 15, b = bh >> 4;
    int m0 = b * LSEQ + c * 64;
    int lane = threadIdx.x;
    const float scale = 0.17677669529663689f;  // 1/sqrt(32)
    if (lane < 32) {
        int i = lane;
        float augi = aug[h * 32 + i];
        size_t base = (size_t)m0 * 512 + h * 32 + i;
        float G = 0.f;
        for (int t = 0; t < 64; t++) {
            float gkv = h2f(gkb[base + (size_t)t * 512]);
            float qv  = h2f(qb [base + (size_t)t * 512]);
            float kv  = h2f(kb [base + (size_t)t * 512]);
            G += gkv;
            G = fmaxf(G, -60.f);
            float en = __expf(-G);
            float ep = __expf(G);
            qqT[t * 32 + i] = qv * ep * scale;
            kkT[t * 32 + i] = kv * en;
            float p = qv * kv * augi;  // aug uses raw q,k
            p += __shfl_xor(p, 1);
            p += __shfl_xor(p, 2);
            p += __shfl_xor(p, 4);
            p += __shfl_xor(p, 8);
            p += __shfl_xor(p, 16);
            if (i == 0) awl[t] = p;
        }
    }
    __syncthreads();
    float T[32];
    size_t sb = (size_t)bhc * 2048 + lane;
#pragma unroll
    for (int i = 0; i < 32; i++) T[i] = Sbuf[sb + i * 64];
    size_t vbase = (size_t)m0 * 1024 + h * 64 + lane;
    for (int t = 0; t < 64; t++) {
        float vj  = h2f(vb [vbase + (size_t)t * 1024]);
        float sgj = h2f(sgb[vbase + (size_t)t * 1024]);
        float aw = awl[t];
        float o = 0.f;
#pragma unroll
        for (int i4 = 0; i4 < 32; i4 += 4) {
            f32x4 kk4 = *(const f32x4*)&kkT[t * 32 + i4];
            f32x4 qq4 = *(const f32x4*)&qqT[t * 32 + i4];
#pragma unroll
            for (int e = 0; e < 4; e++) {
                T[i4 + e] += kk4[e] * vj;    // T_t = S_c + sum kk v
                o += qq4[e] * T[i4 + e];     // o_t = qq_t . T_t
            }
        }
        o += 1.f / (1.f + __expf(-aw * vj));       // + sigmoid(aug_w * v)
        // group norm over dv=64 (all 64 lanes)
        float s1 = o, s2 = o * o;
#pragma unroll
        for (int msk = 1; msk < 64; msk <<= 1) {
            s1 += __shfl_xor(s1, msk);
            s2 += __shfl_xor(s2, msk);
        }
        float mu = s1 * 0.015625f;
        float var = s2 * 0.015625f - mu * mu;
        float on = (o - mu) * rsqrtf(fmaxf(var, 0.f) + 1e-5f);
        PRE[vbase + (size_t)t * 1024] = f2h(on * sgj);
    }
}

// ---------------- host launch ----------------
extern "C" void kernel_launch(void* const* d_in, const int* in_sizes, int n_in,
                              void* d_out, int out_size, void* d_ws, size_t ws_size,
                              hipStream_t stream) {
    (void)in_sizes; (void)n_in; (void)out_size;
    const float* x      = (const float*)d_in[0];
    const float* conv_w = (const float*)d_in[1];
    const float* Wq     = (const float*)d_in[2];
    const float* Wkg    = (const float*)d_in[3];
    const float* Wv     = (const float*)d_in[4];
    const float* Wg     = (const float*)d_in[5];
    const float* bg     = (const float*)d_in[6];
    const float* Wout   = (const float*)d_in[7];
    const float* aug    = (const float*)d_in[8];

    char* ws = (char*)d_ws;
    u16*   xb    = (u16*)  (ws + 0);            // 134217728 B (also PRE later)
    u16*   Wcat  = (u16*)  (ws + 134217728);    //   6291456
    u16*   WoutT = (u16*)  (ws + 140509184);    //   2097152
    u16*   qb    = (u16*)  (ws + 142606336);    //  67108864
    u16*   gkb   = (u16*)  (ws + 209715200);    //  67108864
    u16*   kbuf  = (u16*)  (ws + 276824064);    //  67108864
    u16*   sgb   = (u16*)  (ws + 343932928);    // 134217728
    float* Mbuf  = (float*)(ws + 478150656);    // 134217728
    float* eGC   = (float*)(ws + 612368384);    //   2097152
    float* Sb    = (float*)(ws + 614465536);    // 134217728 (optional)
    const size_t REQ_FULL = 748683264ull;
    int aliased = (ws_size < REQ_FULL) ? 1 : 0;
    float* Sbuf = aliased ? Mbuf : Sb;

    float* out = (float*)d_out;
    float* state_out = out + 67108864;
    u16* vb = (u16*)d_out;  // v (f16) lives in out region until GEMM2 overwrites it

    k_conv_silu<<<dim3(65536), dim3(256), 0, stream>>>(x, conv_w, xb);
    k_packW<<<dim3(16384), dim3(256), 0, stream>>>(Wq, Wkg, Wv, Wg, Wout, Wcat, WoutT);
    k_gemm_bt<1><<<dim3(12288), dim3(256), 0, stream>>>(xb, Wcat, 24,
                                                        qb, gkb, kbuf, vb, sgb, bg, nullptr);
    k_pass1<<<dim3(16384), dim3(64), 0, stream>>>(gkb, kbuf, vb, Mbuf, eGC);
    k_pass2<<<dim3(128), dim3(64), 0, stream>>>(Mbuf, Sbuf, eGC, state_out, aliased);
    k_pass3<<<dim3(16384), dim3(64), 0, stream>>>(qb, gkb, kbuf, vb, sgb, Sbuf, aug, xb /*PRE*/);
    k_gemm_bt<2><<<dim3(4096), dim3(256), 0, stream>>>(xb, WoutT, 8,
                                                       nullptr, nullptr, nullptr, nullptr, nullptr, nullptr, out);
}

// Round 12
// 2153.442 us; speedup vs baseline: 2.0503x; 1.1406x over previous
//
#include <hip/hip_runtime.h>
#include <stdint.h>

typedef __attribute__((ext_vector_type(4))) float f32x4;
typedef _Float16 f16x8 __attribute__((ext_vector_type(8)));
typedef __attribute__((ext_vector_type(2))) unsigned int u32x2;
typedef unsigned short u16;
typedef unsigned int u32;

#define LSEQ 8192
#define BB 8
#define DD 1024
#define MM 65536      // B*L
#define NCH 128       // chunks per sequence (L/64)

__device__ __forceinline__ u16 f2h(float f) {
    _Float16 h = (_Float16)f;
    return *(u16*)&h;
}
__device__ __forceinline__ float h2f(u16 u) {
    _Float16 h = *(_Float16*)&u;
    return (float)h;
}

__device__ __forceinline__ void gload_lds16(const void* g, void* l) {
    __builtin_amdgcn_global_load_lds(
        (const __attribute__((address_space(1))) u32*)g,
        (__attribute__((address_space(3))) u32*)l, 16, 0, 0);
}

// ---------------- conv + silu + transpose -> xb f16 [B*L][D] ----------------
__global__ __launch_bounds__(256) void k_conv_silu(const float* __restrict__ x,
                                                   const float* __restrict__ w,
                                                   u16* __restrict__ xb) {
    int m = blockIdx.x;              // m = b*L + l
    int b = m >> 13, l = m & 8191;
    int d0 = threadIdx.x * 4;
    f32x4 wv[4];
#pragma unroll
    for (int j = 0; j < 4; j++) wv[j] = *(const f32x4*)&w[(d0 + j) * 4];
    float acc[4] = {0.f, 0.f, 0.f, 0.f};
#pragma unroll
    for (int kk = 0; kk < 4; kk++) {
        int lp = l - 3 + kk;
        if (lp >= 0) {
            f32x4 xv = *(const f32x4*)&x[((size_t)(lp * BB + b)) * DD + d0];
#pragma unroll
            for (int j = 0; j < 4; j++) acc[j] += xv[j] * wv[j][kk];
        }
    }
    u16 o[4];
#pragma unroll
    for (int j = 0; j < 4; j++) {
        float a = acc[j];
        o[j] = f2h(a / (1.f + __expf(-a)));
    }
    u32x2 pk;
    pk.x = (u32)o[0] | ((u32)o[1] << 16);
    pk.y = (u32)o[2] | ((u32)o[3] << 16);
    *(u32x2*)&xb[(size_t)m * DD + d0] = pk;
}

// ---------------- pack weights into B^T f16 layouts ----------------
__global__ __launch_bounds__(256) void k_packW(const float* __restrict__ Wq,
                                               const float* __restrict__ Wkg,
                                               const float* __restrict__ Wv,
                                               const float* __restrict__ Wg,
                                               const float* __restrict__ Wout,
                                               u16* __restrict__ Wcat,
                                               u16* __restrict__ WoutT) {
    int idx = blockIdx.x * 256 + threadIdx.x;
    const int T1 = 3072 * 1024;
    if (idx < T1) {
        int n = idx >> 10, kk = idx & 1023;
        float v;
        if (n < 512)        v = Wq [kk * 512 + n];
        else if (n < 1024)  v = Wkg[kk * 512 + (n - 512)];
        else if (n < 2048)  v = Wv [kk * 1024 + (n - 1024)];
        else                v = Wg [kk * 1024 + (n - 2048)];
        Wcat[idx] = f2h(v);
    } else {
        int j = idx - T1;
        if (j < 1024 * 1024) {
            int n = j >> 10, kk = j & 1023;
            WoutT[j] = f2h(Wout[kk * 1024 + n]);
        }
    }
}

// per-fragment epilogue (4 rows x 1 col-group of 16 handled by caller's lr)
template <int MODE>
__device__ __forceinline__ void epi_frag(f32x4 v, int grow0, int gcol,
                                         u16* __restrict__ qo, u16* __restrict__ gko,
                                         u16* __restrict__ ko, u16* __restrict__ vo,
                                         u16* __restrict__ sgo, const float* __restrict__ bg,
                                         float* __restrict__ out) {
#pragma unroll
    for (int rr = 0; rr < 4; rr++) {
        int grow = grow0 + rr;
        float val = v[rr];
        if (MODE == 1) {
            if (gcol < 512) {
                qo[(size_t)grow * 512 + gcol] = f2h(val);
            } else if (gcol < 1024) {
                float ls = fminf(val, 0.f) - log1pf(__expf(-fabsf(val)));
                float gkv = ls * 0.0625f;
                gko[(size_t)grow * 512 + (gcol - 512)] = f2h(gkv);
                ko [(size_t)grow * 512 + (gcol - 512)] = f2h(-expm1f(gkv));
            } else if (gcol < 2048) {
                vo[(size_t)grow * 1024 + (gcol - 1024)] = f2h(val);
            } else {
                float gg = val + bg[gcol - 2048];
                sgo[(size_t)grow * 1024 + (gcol - 2048)] = f2h(gg / (1.f + __expf(-gg)));
            }
        } else {
            int l = grow & 8191, b = grow >> 13;
            out[((size_t)(l * BB + b)) * DD + gcol] = val;
        }
    }
}

// ---------------- f16 GEMM, C = A[M][K] * Bt[N][K]^T, 256x256 tile, BK=32 ----------------
// R11 post-mortem: 128² issue-bound ~420 TF regardless of traffic; R7 256² (830us)
// limited by 1 block/CU lockstep (128 KB LDS). This round: BK 64->32 halves LDS
// to 64 KB -> 2 blocks/CU -> m114 cross-block overlap hides barrier drains.
// Same R7 skeleton: named SSA acc, counted-vmcnt depth-2 staging, T2 swizzle
// adapted to 4-slot rows: src slot (tid&3)^((tid>>3)&3); read col (lk^((lr>>1)&3))*8.
template <int MODE>
__global__ __launch_bounds__(512) void k_gemm_bt(
    const u16* __restrict__ A, const u16* __restrict__ Bt, int nt_tiles,
    u16* __restrict__ qo, u16* __restrict__ gko, u16* __restrict__ ko,
    u16* __restrict__ vo, u16* __restrict__ sgo, const float* __restrict__ bg,
    float* __restrict__ out) {
    const int K = 1024;
    __shared__ __align__(16) u16 Sm[32768];   // 64 KB: [2 buf][A 16KB | B 16KB]
    int tid = threadIdx.x;
    int w = tid >> 6, lane = tid & 63;
    int wm = w >> 2, wn = w & 3;
    int lr = lane & 15, lk = lane >> 4;

    // XCD-aware 2D-blocked tile mapping (R7, measured FETCH ~412 MB = near-ideal)
    int xcd = blockIdx.x & 7;
    int cidx = blockIdx.x >> 3;
    int grpsz = nt_tiles * 4;
    int grp = cidx / grpsz;
    int r = cidx - grp * grpsz;
    int ntile = r >> 2;
    int mts_per_chunk = (gridDim.x >> 3) / nt_tiles;
    int mtile = xcd * mts_per_chunk + grp * 4 + (r & 3);
    int m0 = mtile << 8, n0 = ntile << 8;

#define DECL_ACC(MT) f32x4 a##MT##_0 = {0.f,0.f,0.f,0.f}, a##MT##_1 = {0.f,0.f,0.f,0.f}, \
                           a##MT##_2 = {0.f,0.f,0.f,0.f}, a##MT##_3 = {0.f,0.f,0.f,0.f};
    DECL_ACC(0) DECL_ACC(1) DECL_ACC(2) DECL_ACC(3)
    DECL_ACC(4) DECL_ACC(5) DECL_ACC(6) DECL_ACC(7)
#undef DECL_ACC

    // staging: thread tid covers row (tid>>2)+128p, 16B slot (tid&3)^((tid>>3)&3)
    int gslot = (tid & 3) ^ ((tid >> 3) & 3);
    const u16* gA = A + (size_t)(m0 + (tid >> 2)) * K + gslot * 8;
    const u16* gB = Bt + (size_t)(n0 + (tid >> 2)) * K + gslot * 8;
    char* lA = (char*)Sm + w * 1024;            // HW adds lane*16
    char* lB = (char*)Sm + 16384 + w * 1024;

#define STAGE(TT, OB) { \
    int k1 = (TT) << 5; \
    gload_lds16(gA + k1, lA + (OB)); \
    gload_lds16(gA + (size_t)128 * K + k1, lA + (OB) + 8192); \
    gload_lds16(gB + k1, lB + (OB)); \
    gload_lds16(gB + (size_t)128 * K + k1, lB + (OB) + 8192); }

#define MFMA_ROW(MT) { \
    f16x8 av = *(const f16x8*)&As[(wm * 128 + MT * 16 + lr) * 32 + csl]; \
    a##MT##_0 = __builtin_amdgcn_mfma_f32_16x16x32_f16(av, b0, a##MT##_0, 0, 0, 0); \
    a##MT##_1 = __builtin_amdgcn_mfma_f32_16x16x32_f16(av, b1, a##MT##_1, 0, 0, 0); \
    a##MT##_2 = __builtin_amdgcn_mfma_f32_16x16x32_f16(av, b2, a##MT##_2, 0, 0, 0); \
    a##MT##_3 = __builtin_amdgcn_mfma_f32_16x16x32_f16(av, b3, a##MT##_3, 0, 0, 0); }

#define COMPUTE() { \
    int csl = (lk ^ ((lr >> 1) & 3)) * 8; \
    f16x8 b0 = *(const f16x8*)&Bs[(wn * 64 +  0 + lr) * 32 + csl]; \
    f16x8 b1 = *(const f16x8*)&Bs[(wn * 64 + 16 + lr) * 32 + csl]; \
    f16x8 b2 = *(const f16x8*)&Bs[(wn * 64 + 32 + lr) * 32 + csl]; \
    f16x8 b3 = *(const f16x8*)&Bs[(wn * 64 + 48 + lr) * 32 + csl]; \
    __builtin_amdgcn_s_setprio(1); \
    MFMA_ROW(0) MFMA_ROW(1) MFMA_ROW(2) MFMA_ROW(3) \
    MFMA_ROW(4) MFMA_ROW(5) MFMA_ROW(6) MFMA_ROW(7) \
    __builtin_amdgcn_s_setprio(0); }

    // prologue: stage K-tiles 0 and 1 (8 loads in flight per thread)
    STAGE(0, 0)
    STAGE(1, 32768)

    for (int t = 0; t < 31; ++t) {
        // wait own stage(t) loads only; stage(t+1)'s 4 stay in flight
        asm volatile("s_waitcnt vmcnt(4)" ::: "memory");
        __builtin_amdgcn_sched_barrier(0);
        __builtin_amdgcn_s_barrier();   // all waves' tile-t writes landed
        {
            const u16* As = Sm + (t & 1) * 16384;
            const u16* Bs = As + 8192;
            COMPUTE()
        }
        __builtin_amdgcn_s_barrier();   // buf(t&1) fully consumed
        __builtin_amdgcn_sched_barrier(0);
        if (t < 30) {
            STAGE(t + 2, (t & 1) * 32768)
        }
    }
    // tile 31 (buf 1): everything must be in
    asm volatile("s_waitcnt vmcnt(0)" ::: "memory");
    __builtin_amdgcn_sched_barrier(0);
    __builtin_amdgcn_s_barrier();
    {
        const u16* As = Sm + 16384;
        const u16* Bs = As + 8192;
        COMPUTE()
    }
#undef COMPUTE
#undef MFMA_ROW
#undef STAGE

#define EPI_ROW(MT) { \
    int gr0 = m0 + wm * 128 + MT * 16 + lk * 4; \
    epi_frag<MODE>(a##MT##_0, gr0, n0 + wn * 64 +  0 + lr, qo, gko, ko, vo, sgo, bg, out); \
    epi_frag<MODE>(a##MT##_1, gr0, n0 + wn * 64 + 16 + lr, qo, gko, ko, vo, sgo, bg, out); \
    epi_frag<MODE>(a##MT##_2, gr0, n0 + wn * 64 + 32 + lr, qo, gko, ko, vo, sgo, bg, out); \
    epi_frag<MODE>(a##MT##_3, gr0, n0 + wn * 64 + 48 + lr, qo, gko, ko, vo, sgo, bg, out); }
    EPI_ROW(0) EPI_ROW(1) EPI_ROW(2) EPI_ROW(3)
    EPI_ROW(4) EPI_ROW(5) EPI_ROW(6) EPI_ROW(7)
#undef EPI_ROW
}

// ---------------- pass1: per-chunk increment M_c = sum_s k_s e^{G_C - G_s} v_s^T ----------------
__global__ __launch_bounds__(64) void k_pass1(const u16* __restrict__ gkb,
                                              const u16* __restrict__ kb,
                                              const u16* __restrict__ vb,
                                              float* __restrict__ Mo,
                                              float* __restrict__ eGC) {
    __shared__ __align__(16) float kkT[64 * 32];  // [t][i] fp32
    int bhc = blockIdx.x;
    int c = bhc & 127, bh = bhc >> 7;
    int h = bh & 15, b = bh >> 4;
    int m0 = b * LSEQ + c * 64;
    int lane = threadIdx.x;
    if (lane < 32) {
        int i = lane;
        size_t base = (size_t)m0 * 512 + h * 32 + i;
        float G = 0.f;
        for (int t = 0; t < 64; t++) {
            G += h2f(gkb[base + (size_t)t * 512]);
            G = fmaxf(G, -60.f);
            kkT[t * 32 + i] = h2f(kb[base + (size_t)t * 512]) * __expf(-G);
        }
        eGC[bhc * 32 + i] = __expf(G);
    }
    __syncthreads();
    float Ma[32];
#pragma unroll
    for (int i = 0; i < 32; i++) Ma[i] = 0.f;
    size_t vbase = (size_t)m0 * 1024 + h * 64 + lane;
    for (int t = 0; t < 64; t++) {
        float vj = h2f(vb[vbase + (size_t)t * 1024]);
#pragma unroll
        for (int i4 = 0; i4 < 32; i4 += 4) {
            f32x4 kk4 = *(const f32x4*)&kkT[t * 32 + i4];
            Ma[i4 + 0] += kk4[0] * vj;
            Ma[i4 + 1] += kk4[1] * vj;
            Ma[i4 + 2] += kk4[2] * vj;
            Ma[i4 + 3] += kk4[3] * vj;
        }
    }
    size_t mb = (size_t)bhc * 2048 + lane;
#pragma unroll
    for (int i = 0; i < 32; i++) Mo[mb + i * 64] = Ma[i];
}

// ---------------- pass2: chunk-level recurrence (sequential over 128 chunks) ----------------
__global__ __launch_bounds__(64) void k_pass2(float* Mbuf, float* Sbuf,
                                              const float* __restrict__ eGC,
                                              float* __restrict__ state_out, int aliased) {
    int bh = blockIdx.x;
    int j = threadIdx.x;
    float S[32];
#pragma unroll
    for (int i = 0; i < 32; i++) S[i] = 0.f;
    for (int c = 0; c < NCH; c++) {
        size_t base = ((size_t)bh * NCH + c) * 2048;
        float mv[32], ev[32];
#pragma unroll
        for (int i = 0; i < 32; i++) mv[i] = Mbuf[base + i * 64 + j];
#pragma unroll
        for (int i = 0; i < 32; i++) ev[i] = eGC[(bh * NCH + c) * 32 + i];
        if (aliased) { asm volatile("s_waitcnt vmcnt(0)" ::: "memory"); }
#pragma unroll
        for (int i = 0; i < 32; i++) Sbuf[base + i * 64 + j] = S[i];  // chunk-START state
#pragma unroll
        for (int i = 0; i < 32; i++) S[i] = (S[i] + mv[i]) * ev[i];
    }
    size_t so = (size_t)bh * 2048 + j;
#pragma unroll
    for (int i = 0; i < 32; i++) state_out[so + i * 64] = S[i];
}

// ---------------- pass3: intra-chunk outputs + aug + groupnorm + silu-gate ----------------
__global__ __launch_bounds__(64) void k_pass3(const u16* __restrict__ qb,
                                              const u16* __restrict__ gkb,
                                              const u16* __restrict__ kb,
                                              const u16* __restrict__ vb,
                                              const u16* __restrict__ sgb,
                                              const float* __restrict__ Sbuf,
                                              const float* __restrict__ aug,
                                              u16* __restrict__ PRE) {
    __shared__ __align__(16) float qqT[64 * 32];  // [t][i] fp32
    __shared__ __align__(16) float kkT[64 * 32];
    __shared__ float awl[64];
    int bhc = blockIdx.x;
    int c = bhc & 127, bh = bhc >> 7;
    int h = bh & 15, b = bh >> 4;
    int m0 = b * LSEQ + c * 64;
    int lane = threadIdx.x;
    const float scale = 0.17677669529663689f;  // 1/sqrt(32)
    if (lane < 32) {
        int i = lane;
        float augi = aug[h * 32 + i];
        size_t base = (size_t)m0 * 512 + h * 32 + i;
        float G = 0.f;
        for (int t = 0; t < 64; t++) {
            float gkv = h2f(gkb[base + (size_t)t * 512]);
            float qv  = h2f(qb [base + (size_t)t * 512]);
            float kv  = h2f(kb [base + (size_t)t * 512]);
            G += gkv;
            G = fmaxf(G, -60.f);
            float en = __expf(-G);
            float ep = __expf(G);
            qqT[t * 32 + i] = qv * ep * scale;
            kkT[t * 32 + i] = kv * en;
            float p = qv * kv * augi;  // aug uses raw q,k
            p += __shfl_xor(p, 1);
            p += __shfl_xor(p, 2);
            p += __shfl_xor(p, 4);
            p += __shfl_xor(p, 8);
            p += __shfl_xor(p, 16);
            if (i == 0) awl[t] = p;
        }
    }
    __syncthreads();
    float T[32];
    size_t sb = (size_t)bhc * 2048 + lane;
#pragma unroll
    for (int i = 0; i < 32; i++) T[i] = Sbuf[sb + i * 64];
    size_t vbase = (size_t)m0 * 1024 + h * 64 + lane;
    for (int t = 0; t < 64; t++) {
        float vj  = h2f(vb [vbase + (size_t)t * 1024]);
        float sgj = h2f(sgb[vbase + (size_t)t * 1024]);
        float aw = awl[t];
        float o = 0.f;
#pragma unroll
        for (int i4 = 0; i4 < 32; i4 += 4) {
            f32x4 kk4 = *(const f32x4*)&kkT[t * 32 + i4];
            f32x4 qq4 = *(const f32x4*)&qqT[t * 32 + i4];
#pragma unroll
            for (int e = 0; e < 4; e++) {
                T[i4 + e] += kk4[e] * vj;    // T_t = S_c + sum kk v
                o += qq4[e] * T[i4 + e];     // o_t = qq_t . T_t
            }
        }
        o += 1.f / (1.f + __expf(-aw * vj));       // + sigmoid(aug_w * v)
        // group norm over dv=64 (all 64 lanes)
        float s1 = o, s2 = o * o;
#pragma unroll
        for (int msk = 1; msk < 64; msk <<= 1) {
            s1 += __shfl_xor(s1, msk);
            s2 += __shfl_xor(s2, msk);
        }
        float mu = s1 * 0.015625f;
        float var = s2 * 0.015625f - mu * mu;
        float on = (o - mu) * rsqrtf(fmaxf(var, 0.f) + 1e-5f);
        PRE[vbase + (size_t)t * 1024] = f2h(on * sgj);
    }
}

// ---------------- host launch ----------------
extern "C" void kernel_launch(void* const* d_in, const int* in_sizes, int n_in,
                              void* d_out, int out_size, void* d_ws, size_t ws_size,
                              hipStream_t stream) {
    (void)in_sizes; (void)n_in; (void)out_size;
    const float* x      = (const float*)d_in[0];
    const float* conv_w = (const float*)d_in[1];
    const float* Wq     = (const float*)d_in[2];
    const float* Wkg    = (const float*)d_in[3];
    const float* Wv     = (const float*)d_in[4];
    const float* Wg     = (const float*)d_in[5];
    const float* bg     = (const float*)d_in[6];
    const float* Wout   = (const float*)d_in[7];
    const float* aug    = (const float*)d_in[8];

    char* ws = (char*)d_ws;
    u16*   xb    = (u16*)  (ws + 0);            // 134217728 B (also PRE later)
    u16*   Wcat  = (u16*)  (ws + 134217728);    //   6291456
    u16*   WoutT = (u16*)  (ws + 140509184);    //   2097152
    u16*   qb    = (u16*)  (ws + 142606336);    //  67108864
    u16*   gkb   = (u16*)  (ws + 209715200);    //  67108864
    u16*   kbuf  = (u16*)  (ws + 276824064);    //  67108864
    u16*   sgb   = (u16*)  (ws + 343932928);    // 134217728
    float* Mbuf  = (float*)(ws + 478150656);    // 134217728
    float* eGC   = (float*)(ws + 612368384);    //   2097152
    float* Sb    = (float*)(ws + 614465536);    // 134217728 (optional)
    const size_t REQ_FULL = 748683264ull;
    int aliased = (ws_size < REQ_FULL) ? 1 : 0;
    float* Sbuf = aliased ? Mbuf : Sb;

    float* out = (float*)d_out;
    float* state_out = out + 67108864;
    u16* vb = (u16*)d_out;  // v (f16) lives in out region until GEMM2 overwrites it

    k_conv_silu<<<dim3(65536), dim3(256), 0, stream>>>(x, conv_w, xb);
    k_packW<<<dim3(16384), dim3(256), 0, stream>>>(Wq, Wkg, Wv, Wg, Wout, Wcat, WoutT);
    k_gemm_bt<1><<<dim3(3072), dim3(512), 0, stream>>>(xb, Wcat, 12,
                                                       qb, gkb, kbuf, vb, sgb, bg, nullptr);
    k_pass1<<<dim3(16384), dim3(64), 0, stream>>>(gkb, kbuf, vb, Mbuf, eGC);
    k_pass2<<<dim3(128), dim3(64), 0, stream>>>(Mbuf, Sbuf, eGC, state_out, aliased);
    k_pass3<<<dim3(16384), dim3(64), 0, stream>>>(qb, gkb, kbuf, vb, sgb, Sbuf, aug, xb /*PRE*/);
    k_gemm_bt<2><<<dim3(1024), dim3(512), 0, stream>>>(xb, WoutT, 4,
                                                       nullptr, nullptr, nullptr, nullptr, nullptr, nullptr, out);
}

// Round 13
// 2128.961 us; speedup vs baseline: 2.0739x; 1.0115x over previous
//
#include <hip/hip_runtime.h>
#include <stdint.h>

typedef __attribute__((ext_vector_type(4))) float f32x4;
typedef _Float16 f16x8 __attribute__((ext_vector_type(8)));
typedef __attribute__((ext_vector_type(2))) unsigned int u32x2;
typedef unsigned short u16;
typedef unsigned int u32;

#define LSEQ 8192
#define BB 8
#define DD 1024
#define MM 65536      // B*L
#define NCH 128       // chunks per sequence (L/64)

__device__ __forceinline__ u16 f2h(float f) {
    _Float16 h = (_Float16)f;
    return *(u16*)&h;
}
__device__ __forceinline__ float h2f(u16 u) {
    _Float16 h = *(_Float16*)&u;
    return (float)h;
}

__device__ __forceinline__ void gload_lds16(const void* g, void* l) {
    __builtin_amdgcn_global_load_lds(
        (const __attribute__((address_space(1))) u32*)g,
        (__attribute__((address_space(3))) u32*)l, 16, 0, 0);
}

// ---------------- conv + silu + transpose -> xb f16 [B*L][D] ----------------
__global__ __launch_bounds__(256) void k_conv_silu(const float* __restrict__ x,
                                                   const float* __restrict__ w,
                                                   u16* __restrict__ xb) {
    int m = blockIdx.x;              // m = b*L + l
    int b = m >> 13, l = m & 8191;
    int d0 = threadIdx.x * 4;
    f32x4 wv[4];
#pragma unroll
    for (int j = 0; j < 4; j++) wv[j] = *(const f32x4*)&w[(d0 + j) * 4];
    float acc[4] = {0.f, 0.f, 0.f, 0.f};
#pragma unroll
    for (int kk = 0; kk < 4; kk++) {
        int lp = l - 3 + kk;
        if (lp >= 0) {
            f32x4 xv = *(const f32x4*)&x[((size_t)(lp * BB + b)) * DD + d0];
#pragma unroll
            for (int j = 0; j < 4; j++) acc[j] += xv[j] * wv[j][kk];
        }
    }
    u16 o[4];
#pragma unroll
    for (int j = 0; j < 4; j++) {
        float a = acc[j];
        o[j] = f2h(a / (1.f + __expf(-a)));
    }
    u32x2 pk;
    pk.x = (u32)o[0] | ((u32)o[1] << 16);
    pk.y = (u32)o[2] | ((u32)o[3] << 16);
    *(u32x2*)&xb[(size_t)m * DD + d0] = pk;
}

// ---------------- pack weights into B^T f16 layouts ----------------
__global__ __launch_bounds__(256) void k_packW(const float* __restrict__ Wq,
                                               const float* __restrict__ Wkg,
                                               const float* __restrict__ Wv,
                                               const float* __restrict__ Wg,
                                               const float* __restrict__ Wout,
                                               u16* __restrict__ Wcat,
                                               u16* __restrict__ WoutT) {
    int idx = blockIdx.x * 256 + threadIdx.x;
    const int T1 = 3072 * 1024;
    if (idx < T1) {
        int n = idx >> 10, kk = idx & 1023;
        float v;
        if (n < 512)        v = Wq [kk * 512 + n];
        else if (n < 1024)  v = Wkg[kk * 512 + (n - 512)];
        else if (n < 2048)  v = Wv [kk * 1024 + (n - 1024)];
        else                v = Wg [kk * 1024 + (n - 2048)];
        Wcat[idx] = f2h(v);
    } else {
        int j = idx - T1;
        if (j < 1024 * 1024) {
            int n = j >> 10, kk = j & 1023;
            WoutT[j] = f2h(Wout[kk * 1024 + n]);
        }
    }
}

// per-fragment epilogue (4 rows x 1 col-group of 16 handled by caller's lr)
template <int MODE>
__device__ __forceinline__ void epi_frag(f32x4 v, int grow0, int gcol,
                                         u16* __restrict__ qo, u16* __restrict__ gko,
                                         u16* __restrict__ ko, u16* __restrict__ vo,
                                         u16* __restrict__ sgo, const float* __restrict__ bg,
                                         float* __restrict__ out) {
#pragma unroll
    for (int rr = 0; rr < 4; rr++) {
        int grow = grow0 + rr;
        float val = v[rr];
        if (MODE == 1) {
            if (gcol < 512) {
                qo[(size_t)grow * 512 + gcol] = f2h(val);
            } else if (gcol < 1024) {
                float ls = fminf(val, 0.f) - log1pf(__expf(-fabsf(val)));
                float gkv = ls * 0.0625f;
                gko[(size_t)grow * 512 + (gcol - 512)] = f2h(gkv);
                ko [(size_t)grow * 512 + (gcol - 512)] = f2h(-expm1f(gkv));
            } else if (gcol < 2048) {
                vo[(size_t)grow * 1024 + (gcol - 1024)] = f2h(val);
            } else {
                float gg = val + bg[gcol - 2048];
                sgo[(size_t)grow * 1024 + (gcol - 2048)] = f2h(gg / (1.f + __expf(-gg)));
            }
        } else {
            int l = grow & 8191, b = grow >> 13;
            out[((size_t)(l * BB + b)) * DD + gcol] = val;
        }
    }
}

// ---------------- f16 GEMM, C = A[M][K] * Bt[N][K]^T, 256x128 tile, BK=32 ----------------
// R12 post-mortem: per-SIMD VGPR pool = 512/wave-slot (m69: waves/CU 16@128, 8@256);
// 112 VGPR + 128 AGPR acc => 2 waves/SIMD hard cap => exactly ONE 8-wave block/CU
// => lockstep phases (LDS-flood then MFMA-flood, 10.4k cyc/step vs 2.5k ideal).
// This round: SAME per-wave resources but packaged as TWO INDEPENDENT 4-wave blocks:
// 256x128 tile, BK=32, 4 waves (2M x 2N, per-wave 128x64 as before). LDS padded to
// 56 KB => exactly 2 blocks/CU; no shared barrier between blocks => they drift into
// complementary phases and overlap LDS-read with MFMA across blocks (m114).
template <int MODE>
__global__ __launch_bounds__(256, 2) void k_gemm_bt(
    const u16* __restrict__ A, const u16* __restrict__ Bt, int nt_tiles,
    u16* __restrict__ qo, u16* __restrict__ gko, u16* __restrict__ ko,
    u16* __restrict__ vo, u16* __restrict__ sgo, const float* __restrict__ bg,
    float* __restrict__ out) {
    const int K = 1024;
    // 2 bufs x 24 KB @ 0 / 24576; padded to 56 KB so only 2 blocks/CU fit.
    __shared__ __align__(16) u16 Sm[28672];
    int tid = threadIdx.x;
    int w = tid >> 6, lane = tid & 63;
    int wm = w >> 1, wn = w & 1;
    int lr = lane & 15, lk = lane >> 4;

    // XCD-aware 2D-blocked tile mapping
    int xcd = blockIdx.x & 7;
    int cidx = blockIdx.x >> 3;
    int grpsz = nt_tiles * 4;
    int grp = cidx / grpsz;
    int r = cidx - grp * grpsz;
    int ntile = r >> 2;
    int mts_per_chunk = (gridDim.x >> 3) / nt_tiles;   // 32
    int mtile = xcd * mts_per_chunk + grp * 4 + (r & 3);
    int m0 = mtile << 8, n0 = ntile << 7;

#define DECL_ACC(MT) f32x4 a##MT##_0 = {0.f,0.f,0.f,0.f}, a##MT##_1 = {0.f,0.f,0.f,0.f}, \
                           a##MT##_2 = {0.f,0.f,0.f,0.f}, a##MT##_3 = {0.f,0.f,0.f,0.f};
    DECL_ACC(0) DECL_ACC(1) DECL_ACC(2) DECL_ACC(3)
    DECL_ACC(4) DECL_ACC(5) DECL_ACC(6) DECL_ACC(7)
#undef DECL_ACC

    // staging: thread tid covers row tid>>2 (+p*64), 16B slot (tid&3)^((tid>>3)&3)
    int gslot = (tid & 3) ^ ((tid >> 3) & 3);
    const u16* gA = A + (size_t)(m0 + (tid >> 2)) * K + gslot * 8;
    const u16* gB = Bt + (size_t)(n0 + (tid >> 2)) * K + gslot * 8;
    char* lA = (char*)Sm + w * 1024;            // HW adds lane*16
    char* lB = (char*)Sm + 16384 + w * 1024;

// 6 gloads: A rows 0..255 (4 x 4KB), B rows 0..127 (2 x 4KB)
#define STAGE(TT, OB) { \
    int k1 = (TT) << 5; \
    gload_lds16(gA + k1, lA + (OB)); \
    gload_lds16(gA + (size_t)64 * K + k1, lA + (OB) + 4096); \
    gload_lds16(gA + (size_t)128 * K + k1, lA + (OB) + 8192); \
    gload_lds16(gA + (size_t)192 * K + k1, lA + (OB) + 12288); \
    gload_lds16(gB + k1, lB + (OB)); \
    gload_lds16(gB + (size_t)64 * K + k1, lB + (OB) + 4096); }

#define MFMA_ROW(MT) { \
    f16x8 av = *(const f16x8*)&As[(wm * 128 + MT * 16 + lr) * 32 + csl]; \
    a##MT##_0 = __builtin_amdgcn_mfma_f32_16x16x32_f16(av, b0, a##MT##_0, 0, 0, 0); \
    a##MT##_1 = __builtin_amdgcn_mfma_f32_16x16x32_f16(av, b1, a##MT##_1, 0, 0, 0); \
    a##MT##_2 = __builtin_amdgcn_mfma_f32_16x16x32_f16(av, b2, a##MT##_2, 0, 0, 0); \
    a##MT##_3 = __builtin_amdgcn_mfma_f32_16x16x32_f16(av, b3, a##MT##_3, 0, 0, 0); }

#define COMPUTE() { \
    int csl = (lk ^ ((lr >> 1) & 3)) * 8; \
    f16x8 b0 = *(const f16x8*)&Bs[(wn * 64 +  0 + lr) * 32 + csl]; \
    f16x8 b1 = *(const f16x8*)&Bs[(wn * 64 + 16 + lr) * 32 + csl]; \
    f16x8 b2 = *(const f16x8*)&Bs[(wn * 64 + 32 + lr) * 32 + csl]; \
    f16x8 b3 = *(const f16x8*)&Bs[(wn * 64 + 48 + lr) * 32 + csl]; \
    __builtin_amdgcn_s_setprio(1); \
    MFMA_ROW(0) MFMA_ROW(1) MFMA_ROW(2) MFMA_ROW(3) \
    MFMA_ROW(4) MFMA_ROW(5) MFMA_ROW(6) MFMA_ROW(7) \
    __builtin_amdgcn_s_setprio(0); }

    // prologue: stage K-tiles 0 and 1 (12 loads in flight per thread)
    STAGE(0, 0)
    STAGE(1, 24576)

    for (int t = 0; t < 31; ++t) {
        // wait own stage(t) loads only; stage(t+1)'s 6 stay in flight
        asm volatile("s_waitcnt vmcnt(6)" ::: "memory");
        __builtin_amdgcn_sched_barrier(0);
        __builtin_amdgcn_s_barrier();   // all waves' tile-t writes landed
        {
            const u16* As = Sm + (t & 1) * 12288;
            const u16* Bs = As + 8192;
            COMPUTE()
        }
        __builtin_amdgcn_s_barrier();   // buf(t&1) fully consumed
        __builtin_amdgcn_sched_barrier(0);
        if (t < 30) {
            STAGE(t + 2, (t & 1) * 24576)
        }
    }
    // tile 31 (buf 1): everything must be in
    asm volatile("s_waitcnt vmcnt(0)" ::: "memory");
    __builtin_amdgcn_sched_barrier(0);
    __builtin_amdgcn_s_barrier();
    {
        const u16* As = Sm + 12288;
        const u16* Bs = As + 8192;
        COMPUTE()
    }
#undef COMPUTE
#undef MFMA_ROW
#undef STAGE

#define EPI_ROW(MT) { \
    int gr0 = m0 + wm * 128 + MT * 16 + lk * 4; \
    epi_frag<MODE>(a##MT##_0, gr0, n0 + wn * 64 +  0 + lr, qo, gko, ko, vo, sgo, bg, out); \
    epi_frag<MODE>(a##MT##_1, gr0, n0 + wn * 64 + 16 + lr, qo, gko, ko, vo, sgo, bg, out); \
    epi_frag<MODE>(a##MT##_2, gr0, n0 + wn * 64 + 32 + lr, qo, gko, ko, vo, sgo, bg, out); \
    epi_frag<MODE>(a##MT##_3, gr0, n0 + wn * 64 + 48 + lr, qo, gko, ko, vo, sgo, bg, out); }
    EPI_ROW(0) EPI_ROW(1) EPI_ROW(2) EPI_ROW(3)
    EPI_ROW(4) EPI_ROW(5) EPI_ROW(6) EPI_ROW(7)
#undef EPI_ROW
}

// ---------------- pass1: per-chunk increment M_c = sum_s k_s e^{G_C - G_s} v_s^T ----------------
__global__ __launch_bounds__(64) void k_pass1(const u16* __restrict__ gkb,
                                              const u16* __restrict__ kb,
                                              const u16* __restrict__ vb,
                                              float* __restrict__ Mo,
                                              float* __restrict__ eGC) {
    __shared__ __align__(16) float kkT[64 * 32];  // [t][i] fp32
    int bhc = blockIdx.x;
    int c = bhc & 127, bh = bhc >> 7;
    int h = bh & 15, b = bh >> 4;
    int m0 = b * LSEQ + c * 64;
    int lane = threadIdx.x;
    if (lane < 32) {
        int i = lane;
        size_t base = (size_t)m0 * 512 + h * 32 + i;
        float G = 0.f;
        for (int t = 0; t < 64; t++) {
            G += h2f(gkb[base + (size_t)t * 512]);
            G = fmaxf(G, -60.f);
            kkT[t * 32 + i] = h2f(kb[base + (size_t)t * 512]) * __expf(-G);
        }
        eGC[bhc * 32 + i] = __expf(G);
    }
    __syncthreads();
    float Ma[32];
#pragma unroll
    for (int i = 0; i < 32; i++) Ma[i] = 0.f;
    size_t vbase = (size_t)m0 * 1024 + h * 64 + lane;
    for (int t = 0; t < 64; t++) {
        float vj = h2f(vb[vbase + (size_t)t * 1024]);
#pragma unroll
        for (int i4 = 0; i4 < 32; i4 += 4) {
            f32x4 kk4 = *(const f32x4*)&kkT[t * 32 + i4];
            Ma[i4 + 0] += kk4[0] * vj;
            Ma[i4 + 1] += kk4[1] * vj;
            Ma[i4 + 2] += kk4[2] * vj;
            Ma[i4 + 3] += kk4[3] * vj;
        }
    }
    size_t mb = (size_t)bhc * 2048 + lane;
#pragma unroll
    for (int i = 0; i < 32; i++) Mo[mb + i * 64] = Ma[i];
}

// ---------------- pass2: chunk-level recurrence (sequential over 128 chunks) ----------------
__global__ __launch_bounds__(64) void k_pass2(float* Mbuf, float* Sbuf,
                                              const float* __restrict__ eGC,
                                              float* __restrict__ state_out, int aliased) {
    int bh = blockIdx.x;
    int j = threadIdx.x;
    float S[32];
#pragma unroll
    for (int i = 0; i < 32; i++) S[i] = 0.f;
    for (int c = 0; c < NCH; c++) {
        size_t base = ((size_t)bh * NCH + c) * 2048;
        float mv[32], ev[32];
#pragma unroll
        for (int i = 0; i < 32; i++) mv[i] = Mbuf[base + i * 64 + j];
#pragma unroll
        for (int i = 0; i < 32; i++) ev[i] = eGC[(bh * NCH + c) * 32 + i];
        if (aliased) { asm volatile("s_waitcnt vmcnt(0)" ::: "memory"); }
#pragma unroll
        for (int i = 0; i < 32; i++) Sbuf[base + i * 64 + j] = S[i];  // chunk-START state
#pragma unroll
        for (int i = 0; i < 32; i++) S[i] = (S[i] + mv[i]) * ev[i];
    }
    size_t so = (size_t)bh * 2048 + j;
#pragma unroll
    for (int i = 0; i < 32; i++) state_out[so + i * 64] = S[i];
}

// ---------------- pass3: intra-chunk outputs + aug + groupnorm + silu-gate ----------------
__global__ __launch_bounds__(64) void k_pass3(const u16* __restrict__ qb,
                                              const u16* __restrict__ gkb,
                                              const u16* __restrict__ kb,
                                              const u16* __restrict__ vb,
                                              const u16* __restrict__ sgb,
                                              const float* __restrict__ Sbuf,
                                              const float* __restrict__ aug,
                                              u16* __restrict__ PRE) {
    __shared__ __align__(16) float qqT[64 * 32];  // [t][i] fp32
    __shared__ __align__(16) float kkT[64 * 32];
    __shared__ float awl[64];
    int bhc = blockIdx.x;
    int c = bhc & 127, bh = bhc >> 7;
    int h = bh & 15, b = bh >> 4;
    int m0 = b * LSEQ + c * 64;
    int lane = threadIdx.x;
    const float scale = 0.17677669529663689f;  // 1/sqrt(32)
    if (lane < 32) {
        int i = lane;
        float augi = aug[h * 32 + i];
        size_t base = (size_t)m0 * 512 + h * 32 + i;
        float G = 0.f;
        for (int t = 0; t < 64; t++) {
            float gkv = h2f(gkb[base + (size_t)t * 512]);
            float qv  = h2f(qb [base + (size_t)t * 512]);
            float kv  = h2f(kb [base + (size_t)t * 512]);
            G += gkv;
            G = fmaxf(G, -60.f);
            float en = __expf(-G);
            float ep = __expf(G);
            qqT[t * 32 + i] = qv * ep * scale;
            kkT[t * 32 + i] = kv * en;
            float p = qv * kv * augi;  // aug uses raw q,k
            p += __shfl_xor(p, 1);
            p += __shfl_xor(p, 2);
            p += __shfl_xor(p, 4);
            p += __shfl_xor(p, 8);
            p += __shfl_xor(p, 16);
            if (i == 0) awl[t] = p;
        }
    }
    __syncthreads();
    float T[32];
    size_t sb = (size_t)bhc * 2048 + lane;
#pragma unroll
    for (int i = 0; i < 32; i++) T[i] = Sbuf[sb + i * 64];
    size_t vbase = (size_t)m0 * 1024 + h * 64 + lane;
    for (int t = 0; t < 64; t++) {
        float vj  = h2f(vb [vbase + (size_t)t * 1024]);
        float sgj = h2f(sgb[vbase + (size_t)t * 1024]);
        float aw = awl[t];
        float o = 0.f;
#pragma unroll
        for (int i4 = 0; i4 < 32; i4 += 4) {
            f32x4 kk4 = *(const f32x4*)&kkT[t * 32 + i4];
            f32x4 qq4 = *(const f32x4*)&qqT[t * 32 + i4];
#pragma unroll
            for (int e = 0; e < 4; e++) {
                T[i4 + e] += kk4[e] * vj;    // T_t = S_c + sum kk v
                o += qq4[e] * T[i4 + e];     // o_t = qq_t . T_t
            }
        }
        o += 1.f / (1.f + __expf(-aw * vj));       // + sigmoid(aug_w * v)
        // group norm over dv=64 (all 64 lanes)
        float s1 = o, s2 = o * o;
#pragma unroll
        for (int msk = 1; msk < 64; msk <<= 1) {
            s1 += __shfl_xor(s1, msk);
            s2 += __shfl_xor(s2, msk);
        }
        float mu = s1 * 0.015625f;
        float var = s2 * 0.015625f - mu * mu;
        float on = (o - mu) * rsqrtf(fmaxf(var, 0.f) + 1e-5f);
        PRE[vbase + (size_t)t * 1024] = f2h(on * sgj);
    }
}

// ---------------- host launch ----------------
extern "C" void kernel_launch(void* const* d_in, const int* in_sizes, int n_in,
                              void* d_out, int out_size, void* d_ws, size_t ws_size,
                              hipStream_t stream) {
    (void)in_sizes; (void)n_in; (void)out_size;
    const float* x      = (const float*)d_in[0];
    const float* conv_w = (const float*)d_in[1];
    const float* Wq     = (const float*)d_in[2];
    const float* Wkg    = (const float*)d_in[3];
    const float* Wv     = (const float*)d_in[4];
    const float* Wg     = (const float*)d_in[5];
    const float* bg     = (const float*)d_in[6];
    const float* Wout   = (const float*)d_in[7];
    const float* aug    = (const float*)d_in[8];

    char* ws = (char*)d_ws;
    u16*   xb    = (u16*)  (ws + 0);            // 134217728 B (also PRE later)
    u16*   Wcat  = (u16*)  (ws + 134217728);    //   6291456
    u16*   WoutT = (u16*)  (ws + 140509184);    //   2097152
    u16*   qb    = (u16*)  (ws + 142606336);    //  67108864
    u16*   gkb   = (u16*)  (ws + 209715200);    //  67108864
    u16*   kbuf  = (u16*)  (ws + 276824064);    //  67108864
    u16*   sgb   = (u16*)  (ws + 343932928);    // 134217728
    float* Mbuf  = (float*)(ws + 478150656);    // 134217728
    float* eGC   = (float*)(ws + 612368384);    //   2097152
    float* Sb    = (float*)(ws + 614465536);    // 134217728 (optional)
    const size_t REQ_FULL = 748683264ull;
    int aliased = (ws_size < REQ_FULL) ? 1 : 0;
    float* Sbuf = aliased ? Mbuf : Sb;

    float* out = (float*)d_out;
    float* state_out = out + 67108864;
    u16* vb = (u16*)d_out;  // v (f16) lives in out region until GEMM2 overwrites it

    k_conv_silu<<<dim3(65536), dim3(256), 0, stream>>>(x, conv_w, xb);
    k_packW<<<dim3(16384), dim3(256), 0, stream>>>(Wq, Wkg, Wv, Wg, Wout, Wcat, WoutT);
    k_gemm_bt<1><<<dim3(6144), dim3(256), 0, stream>>>(xb, Wcat, 24,
                                                       qb, gkb, kbuf, vb, sgb, bg, nullptr);
    k_pass1<<<dim3(16384), dim3(64), 0, stream>>>(gkb, kbuf, vb, Mbuf, eGC);
    k_pass2<<<dim3(128), dim3(64), 0, stream>>>(Mbuf, Sbuf, eGC, state_out, aliased);
    k_pass3<<<dim3(16384), dim3(64), 0, stream>>>(qb, gkb, kbuf, vb, sgb, Sbuf, aug, xb /*PRE*/);
    k_gemm_bt<2><<<dim3(2048), dim3(256), 0, stream>>>(xb, WoutT, 8,
                                                       nullptr, nullptr, nullptr, nullptr, nullptr, nullptr, out);
}

// Round 14
// 1820.922 us; speedup vs baseline: 2.4247x; 1.1692x over previous
//
#include <hip/hip_runtime.h>
#include <stdint.h>

typedef __attribute__((ext_vector_type(4))) float f32x4;
typedef _Float16 f16x8 __attribute__((ext_vector_type(8)));
typedef __attribute__((ext_vector_type(8))) unsigned short u16x8;
typedef __attribute__((ext_vector_type(2))) unsigned int u32x2;
typedef unsigned short u16;
typedef unsigned int u32;

#define LSEQ 8192
#define BB 8
#define DD 1024
#define MM 65536      // B*L
#define NCH 128       // chunks per sequence (L/64)

__device__ __forceinline__ u16 f2h(float f) {
    _Float16 h = (_Float16)f;
    return *(u16*)&h;
}
__device__ __forceinline__ float h2f(u16 u) {
    _Float16 h = *(_Float16*)&u;
    return (float)h;
}

__device__ __forceinline__ void gload_lds16(const void* g, void* l) {
    __builtin_amdgcn_global_load_lds(
        (const __attribute__((address_space(1))) u32*)g,
        (__attribute__((address_space(3))) u32*)l, 16, 0, 0);
}

// ---------------- conv + silu + transpose -> xb f16 [B*L][D] ----------------
__global__ __launch_bounds__(256) void k_conv_silu(const float* __restrict__ x,
                                                   const float* __restrict__ w,
                                                   u16* __restrict__ xb) {
    int m = blockIdx.x;              // m = b*L + l
    int b = m >> 13, l = m & 8191;
    int d0 = threadIdx.x * 4;
    f32x4 wv[4];
#pragma unroll
    for (int j = 0; j < 4; j++) wv[j] = *(const f32x4*)&w[(d0 + j) * 4];
    float acc[4] = {0.f, 0.f, 0.f, 0.f};
#pragma unroll
    for (int kk = 0; kk < 4; kk++) {
        int lp = l - 3 + kk;
        if (lp >= 0) {
            f32x4 xv = *(const f32x4*)&x[((size_t)(lp * BB + b)) * DD + d0];
#pragma unroll
            for (int j = 0; j < 4; j++) acc[j] += xv[j] * wv[j][kk];
        }
    }
    u16 o[4];
#pragma unroll
    for (int j = 0; j < 4; j++) {
        float a = acc[j];
        o[j] = f2h(a / (1.f + __expf(-a)));
    }
    u32x2 pk;
    pk.x = (u32)o[0] | ((u32)o[1] << 16);
    pk.y = (u32)o[2] | ((u32)o[3] << 16);
    *(u32x2*)&xb[(size_t)m * DD + d0] = pk;
}

// ---------------- pack weights into B^T f16 layouts ----------------
__global__ __launch_bounds__(256) void k_packW(const float* __restrict__ Wq,
                                               const float* __restrict__ Wkg,
                                               const float* __restrict__ Wv,
                                               const float* __restrict__ Wg,
                                               const float* __restrict__ Wout,
                                               u16* __restrict__ Wcat,
                                               u16* __restrict__ WoutT) {
    int idx = blockIdx.x * 256 + threadIdx.x;
    const int T1 = 3072 * 1024;
    if (idx < T1) {
        int n = idx >> 10, kk = idx & 1023;
        float v;
        if (n < 512)        v = Wq [kk * 512 + n];
        else if (n < 1024)  v = Wkg[kk * 512 + (n - 512)];
        else if (n < 2048)  v = Wv [kk * 1024 + (n - 1024)];
        else                v = Wg [kk * 1024 + (n - 2048)];
        Wcat[idx] = f2h(v);
    } else {
        int j = idx - T1;
        if (j < 1024 * 1024) {
            int n = j >> 10, kk = j & 1023;
            WoutT[j] = f2h(Wout[kk * 1024 + n]);
        }
    }
}

// per-fragment epilogue (4 rows x 1 col-group of 16 handled by caller's lr)
template <int MODE>
__device__ __forceinline__ void epi_frag(f32x4 v, int grow0, int gcol,
                                         u16* __restrict__ qo, u16* __restrict__ gko,
                                         u16* __restrict__ ko, u16* __restrict__ vo,
                                         u16* __restrict__ sgo, const float* __restrict__ bg,
                                         float* __restrict__ out) {
#pragma unroll
    for (int rr = 0; rr < 4; rr++) {
        int grow = grow0 + rr;
        float val = v[rr];
        if (MODE == 1) {
            if (gcol < 512) {
                qo[(size_t)grow * 512 + gcol] = f2h(val);
            } else if (gcol < 1024) {
                float ls = fminf(val, 0.f) - log1pf(__expf(-fabsf(val)));
                float gkv = ls * 0.0625f;
                gko[(size_t)grow * 512 + (gcol - 512)] = f2h(gkv);
                ko [(size_t)grow * 512 + (gcol - 512)] = f2h(-expm1f(gkv));
            } else if (gcol < 2048) {
                vo[(size_t)grow * 1024 + (gcol - 1024)] = f2h(val);
            } else {
                float gg = val + bg[gcol - 2048];
                sgo[(size_t)grow * 1024 + (gcol - 2048)] = f2h(gg / (1.f + __expf(-gg)));
            }
        } else {
            int l = grow & 8191, b = grow >> 13;
            out[((size_t)(l * BB + b)) * DD + gcol] = val;
        }
    }
}

// ---------------- f16 GEMM, C = A[M][K] * Bt[N][K]^T, 256x128 tile, BK=32 ----------------
// (R13 structure, best GEMM so far: two independent 4-wave blocks/CU, ~800us)
template <int MODE>
__global__ __launch_bounds__(256, 2) void k_gemm_bt(
    const u16* __restrict__ A, const u16* __restrict__ Bt, int nt_tiles,
    u16* __restrict__ qo, u16* __restrict__ gko, u16* __restrict__ ko,
    u16* __restrict__ vo, u16* __restrict__ sgo, const float* __restrict__ bg,
    float* __restrict__ out) {
    const int K = 1024;
    // 2 bufs x 24 KB @ 0 / 24576; padded to 56 KB so only 2 blocks/CU fit.
    __shared__ __align__(16) u16 Sm[28672];
    int tid = threadIdx.x;
    int w = tid >> 6, lane = tid & 63;
    int wm = w >> 1, wn = w & 1;
    int lr = lane & 15, lk = lane >> 4;

    // XCD-aware 2D-blocked tile mapping
    int xcd = blockIdx.x & 7;
    int cidx = blockIdx.x >> 3;
    int grpsz = nt_tiles * 4;
    int grp = cidx / grpsz;
    int r = cidx - grp * grpsz;
    int ntile = r >> 2;
    int mts_per_chunk = (gridDim.x >> 3) / nt_tiles;   // 32
    int mtile = xcd * mts_per_chunk + grp * 4 + (r & 3);
    int m0 = mtile << 8, n0 = ntile << 7;

#define DECL_ACC(MT) f32x4 a##MT##_0 = {0.f,0.f,0.f,0.f}, a##MT##_1 = {0.f,0.f,0.f,0.f}, \
                           a##MT##_2 = {0.f,0.f,0.f,0.f}, a##MT##_3 = {0.f,0.f,0.f,0.f};
    DECL_ACC(0) DECL_ACC(1) DECL_ACC(2) DECL_ACC(3)
    DECL_ACC(4) DECL_ACC(5) DECL_ACC(6) DECL_ACC(7)
#undef DECL_ACC

    // staging: thread tid covers row tid>>2 (+p*64), 16B slot (tid&3)^((tid>>3)&3)
    int gslot = (tid & 3) ^ ((tid >> 3) & 3);
    const u16* gA = A + (size_t)(m0 + (tid >> 2)) * K + gslot * 8;
    const u16* gB = Bt + (size_t)(n0 + (tid >> 2)) * K + gslot * 8;
    char* lA = (char*)Sm + w * 1024;            // HW adds lane*16
    char* lB = (char*)Sm + 16384 + w * 1024;

// 6 gloads: A rows 0..255 (4 x 4KB), B rows 0..127 (2 x 4KB)
#define STAGE(TT, OB) { \
    int k1 = (TT) << 5; \
    gload_lds16(gA + k1, lA + (OB)); \
    gload_lds16(gA + (size_t)64 * K + k1, lA + (OB) + 4096); \
    gload_lds16(gA + (size_t)128 * K + k1, lA + (OB) + 8192); \
    gload_lds16(gA + (size_t)192 * K + k1, lA + (OB) + 12288); \
    gload_lds16(gB + k1, lB + (OB)); \
    gload_lds16(gB + (size_t)64 * K + k1, lB + (OB) + 4096); }

#define MFMA_ROW(MT) { \
    f16x8 av = *(const f16x8*)&As[(wm * 128 + MT * 16 + lr) * 32 + csl]; \
    a##MT##_0 = __builtin_amdgcn_mfma_f32_16x16x32_f16(av, b0, a##MT##_0, 0, 0, 0); \
    a##MT##_1 = __builtin_amdgcn_mfma_f32_16x16x32_f16(av, b1, a##MT##_1, 0, 0, 0); \
    a##MT##_2 = __builtin_amdgcn_mfma_f32_16x16x32_f16(av, b2, a##MT##_2, 0, 0, 0); \
    a##MT##_3 = __builtin_amdgcn_mfma_f32_16x16x32_f16(av, b3, a##MT##_3, 0, 0, 0); }

#define COMPUTE() { \
    int csl = (lk ^ ((lr >> 1) & 3)) * 8; \
    f16x8 b0 = *(const f16x8*)&Bs[(wn * 64 +  0 + lr) * 32 + csl]; \
    f16x8 b1 = *(const f16x8*)&Bs[(wn * 64 + 16 + lr) * 32 + csl]; \
    f16x8 b2 = *(const f16x8*)&Bs[(wn * 64 + 32 + lr) * 32 + csl]; \
    f16x8 b3 = *(const f16x8*)&Bs[(wn * 64 + 48 + lr) * 32 + csl]; \
    __builtin_amdgcn_s_setprio(1); \
    MFMA_ROW(0) MFMA_ROW(1) MFMA_ROW(2) MFMA_ROW(3) \
    MFMA_ROW(4) MFMA_ROW(5) MFMA_ROW(6) MFMA_ROW(7) \
    __builtin_amdgcn_s_setprio(0); }

    // prologue: stage K-tiles 0 and 1 (12 loads in flight per thread)
    STAGE(0, 0)
    STAGE(1, 24576)

    for (int t = 0; t < 31; ++t) {
        // wait own stage(t) loads only; stage(t+1)'s 6 stay in flight
        asm volatile("s_waitcnt vmcnt(6)" ::: "memory");
        __builtin_amdgcn_sched_barrier(0);
        __builtin_amdgcn_s_barrier();   // all waves' tile-t writes landed
        {
            const u16* As = Sm + (t & 1) * 12288;
            const u16* Bs = As + 8192;
            COMPUTE()
        }
        __builtin_amdgcn_s_barrier();   // buf(t&1) fully consumed
        __builtin_amdgcn_sched_barrier(0);
        if (t < 30) {
            STAGE(t + 2, (t & 1) * 24576)
        }
    }
    // tile 31 (buf 1): everything must be in
    asm volatile("s_waitcnt vmcnt(0)" ::: "memory");
    __builtin_amdgcn_sched_barrier(0);
    __builtin_amdgcn_s_barrier();
    {
        const u16* As = Sm + 12288;
        const u16* Bs = As + 8192;
        COMPUTE()
    }
#undef COMPUTE
#undef MFMA_ROW
#undef STAGE

#define EPI_ROW(MT) { \
    int gr0 = m0 + wm * 128 + MT * 16 + lk * 4; \
    epi_frag<MODE>(a##MT##_0, gr0, n0 + wn * 64 +  0 + lr, qo, gko, ko, vo, sgo, bg, out); \
    epi_frag<MODE>(a##MT##_1, gr0, n0 + wn * 64 + 16 + lr, qo, gko, ko, vo, sgo, bg, out); \
    epi_frag<MODE>(a##MT##_2, gr0, n0 + wn * 64 + 32 + lr, qo, gko, ko, vo, sgo, bg, out); \
    epi_frag<MODE>(a##MT##_3, gr0, n0 + wn * 64 + 48 + lr, qo, gko, ko, vo, sgo, bg, out); }
    EPI_ROW(0) EPI_ROW(1) EPI_ROW(2) EPI_ROW(3)
    EPI_ROW(4) EPI_ROW(5) EPI_ROW(6) EPI_ROW(7)
#undef EPI_ROW
}

// ---------------- pass1: per-chunk increment M_c = sum_s k_s e^{G_C - G_s} v_s^T ----------------
__global__ __launch_bounds__(64) void k_pass1(const u16* __restrict__ gkb,
                                              const u16* __restrict__ kb,
                                              const u16* __restrict__ vb,
                                              float* __restrict__ Mo,
                                              float* __restrict__ eGC) {
    __shared__ __align__(16) float kkT[64 * 32];  // [t][i] fp32
    int bhc = blockIdx.x;
    int c = bhc & 127, bh = bhc >> 7;
    int h = bh & 15, b = bh >> 4;
    int m0 = b * LSEQ + c * 64;
    int lane = threadIdx.x;
    if (lane < 32) {
        int i = lane;
        size_t base = (size_t)m0 * 512 + h * 32 + i;
        float G = 0.f;
        for (int t = 0; t < 64; t++) {
            G += h2f(gkb[base + (size_t)t * 512]);
            G = fmaxf(G, -60.f);
            kkT[t * 32 + i] = h2f(kb[base + (size_t)t * 512]) * __expf(-G);
        }
        eGC[bhc * 32 + i] = __expf(G);
    }
    __syncthreads();
    float Ma[32];
#pragma unroll
    for (int i = 0; i < 32; i++) Ma[i] = 0.f;
    size_t vbase = (size_t)m0 * 1024 + h * 64 + lane;
    for (int t = 0; t < 64; t++) {
        float vj = h2f(vb[vbase + (size_t)t * 1024]);
#pragma unroll
        for (int i4 = 0; i4 < 32; i4 += 4) {
            f32x4 kk4 = *(const f32x4*)&kkT[t * 32 + i4];
            Ma[i4 + 0] += kk4[0] * vj;
            Ma[i4 + 1] += kk4[1] * vj;
            Ma[i4 + 2] += kk4[2] * vj;
            Ma[i4 + 3] += kk4[3] * vj;
        }
    }
    size_t mb = (size_t)bhc * 2048 + lane;
#pragma unroll
    for (int i = 0; i < 32; i++) Mo[mb + i * 64] = Ma[i];
}

// ---------------- pass2: chunk-level recurrence (sequential over 128 chunks) ----------------
__global__ __launch_bounds__(64) void k_pass2(float* Mbuf, float* Sbuf,
                                              const float* __restrict__ eGC,
                                              float* __restrict__ state_out, int aliased) {
    int bh = blockIdx.x;
    int j = threadIdx.x;
    float S[32];
#pragma unroll
    for (int i = 0; i < 32; i++) S[i] = 0.f;
    for (int c = 0; c < NCH; c++) {
        size_t base = ((size_t)bh * NCH + c) * 2048;
        float mv[32], ev[32];
#pragma unroll
        for (int i = 0; i < 32; i++) mv[i] = Mbuf[base + i * 64 + j];
#pragma unroll
        for (int i = 0; i < 32; i++) ev[i] = eGC[(bh * NCH + c) * 32 + i];
        if (aliased) { asm volatile("s_waitcnt vmcnt(0)" ::: "memory"); }
#pragma unroll
        for (int i = 0; i < 32; i++) Sbuf[base + i * 64 + j] = S[i];  // chunk-START state
#pragma unroll
        for (int i = 0; i < 32; i++) S[i] = (S[i] + mv[i]) * ev[i];
    }
    size_t so = (size_t)bh * 2048 + j;
#pragma unroll
    for (int i = 0; i < 32; i++) state_out[so + i * 64] = S[i];
}

// ---------------- pass3: intra-chunk outputs + aug + groupnorm + silu-gate ----------------
// R13 post-mortem: 815us, MfmaUtil 0, VALUBusy 29%, Occ 24.7% (LDS 16.9KB -> 9
// blocks/CU), serial 5-shfl aug chain on half a wave, 32-deep o-FMA chain.
// Fixes: (1) f16 qqT/kkT -> LDS 8.7KB -> ~18 blocks/CU; (2) aug phase uses all
// 64 lanes, 2 t's per iter (shfl masks <=16 stay in 32-lane halves); (3) o split
// into 4 partials (8-deep chains).
__global__ __launch_bounds__(64) void k_pass3(const u16* __restrict__ qb,
                                              const u16* __restrict__ gkb,
                                              const u16* __restrict__ kb,
                                              const u16* __restrict__ vb,
                                              const u16* __restrict__ sgb,
                                              const float* __restrict__ Sbuf,
                                              const float* __restrict__ aug,
                                              u16* __restrict__ PRE) {
    __shared__ __align__(16) u16 qqT[64 * 32];  // [t][i] f16
    __shared__ __align__(16) u16 kkT[64 * 32];
    __shared__ float awl[64];
    int bhc = blockIdx.x;
    int c = bhc & 127, bh = bhc >> 7;
    int h = bh & 15, b = bh >> 4;
    int m0 = b * LSEQ + c * 64;
    int lane = threadIdx.x;
    const float scale = 0.17677669529663689f;  // 1/sqrt(32)
    // phase 1a: serial-G transform (32 lanes; G prefix is inherently serial in t)
    if (lane < 32) {
        int i = lane;
        size_t base = (size_t)m0 * 512 + h * 32 + i;
        float G = 0.f;
        for (int t = 0; t < 64; t++) {
            float gkv = h2f(gkb[base + (size_t)t * 512]);
            float qv  = h2f(qb [base + (size_t)t * 512]);
            float kv  = h2f(kb [base + (size_t)t * 512]);
            G += gkv;
            G = fmaxf(G, -60.f);
            qqT[t * 32 + i] = f2h(qv * __expf(G) * scale);
            kkT[t * 32 + i] = f2h(kv * __expf(-G));
        }
    }
    // phase 1b: aug weights, all 64 lanes, 2 t's per iteration
    {
        int i = lane & 31;
        int th = (lane >> 5) << 5;     // 0 or 32
        float augi = aug[h * 32 + i];
        size_t base2 = (size_t)m0 * 512 + h * 32 + i;
        for (int tt = 0; tt < 32; tt++) {
            int t = tt + th;
            float qv = h2f(qb[base2 + (size_t)t * 512]);
            float kv = h2f(kb[base2 + (size_t)t * 512]);
            float p = qv * kv * augi;
            p += __shfl_xor(p, 1);
            p += __shfl_xor(p, 2);
            p += __shfl_xor(p, 4);
            p += __shfl_xor(p, 8);
            p += __shfl_xor(p, 16);
            if (i == 0) awl[t] = p;
        }
    }
    __syncthreads();
    float T[32];
    size_t sb = (size_t)bhc * 2048 + lane;
#pragma unroll
    for (int i = 0; i < 32; i++) T[i] = Sbuf[sb + i * 64];
    size_t vbase = (size_t)m0 * 1024 + h * 64 + lane;
    for (int t = 0; t < 64; t++) {
        float vj  = h2f(vb [vbase + (size_t)t * 1024]);
        float sgj = h2f(sgb[vbase + (size_t)t * 1024]);
        float aw = awl[t];
        float o0 = 0.f, o1 = 0.f, o2 = 0.f, o3 = 0.f;
        u16x8 kk8a = *(const u16x8*)&kkT[t * 32 + 0];
        u16x8 qq8a = *(const u16x8*)&qqT[t * 32 + 0];
        u16x8 kk8b = *(const u16x8*)&kkT[t * 32 + 8];
        u16x8 qq8b = *(const u16x8*)&qqT[t * 32 + 8];
        u16x8 kk8c = *(const u16x8*)&kkT[t * 32 + 16];
        u16x8 qq8c = *(const u16x8*)&qqT[t * 32 + 16];
        u16x8 kk8d = *(const u16x8*)&kkT[t * 32 + 24];
        u16x8 qq8d = *(const u16x8*)&qqT[t * 32 + 24];
#pragma unroll
        for (int e = 0; e < 8; e++) {
            T[e]      += h2f(kk8a[e]) * vj;  o0 += h2f(qq8a[e]) * T[e];
            T[8 + e]  += h2f(kk8b[e]) * vj;  o1 += h2f(qq8b[e]) * T[8 + e];
            T[16 + e] += h2f(kk8c[e]) * vj;  o2 += h2f(qq8c[e]) * T[16 + e];
            T[24 + e] += h2f(kk8d[e]) * vj;  o3 += h2f(qq8d[e]) * T[24 + e];
        }
        float o = (o0 + o1) + (o2 + o3);
        o += 1.f / (1.f + __expf(-aw * vj));       // + sigmoid(aug_w * v)
        // group norm over dv=64 (all 64 lanes)
        float s1 = o, s2 = o * o;
#pragma unroll
        for (int msk = 1; msk < 64; msk <<= 1) {
            s1 += __shfl_xor(s1, msk);
            s2 += __shfl_xor(s2, msk);
        }
        float mu = s1 * 0.015625f;
        float var = s2 * 0.015625f - mu * mu;
        float on = (o - mu) * rsqrtf(fmaxf(var, 0.f) + 1e-5f);
        PRE[vbase + (size_t)t * 1024] = f2h(on * sgj);
    }
}

// ---------------- host launch ----------------
extern "C" void kernel_launch(void* const* d_in, const int* in_sizes, int n_in,
                              void* d_out, int out_size, void* d_ws, size_t ws_size,
                              hipStream_t stream) {
    (void)in_sizes; (void)n_in; (void)out_size;
    const float* x      = (const float*)d_in[0];
    const float* conv_w = (const float*)d_in[1];
    const float* Wq     = (const float*)d_in[2];
    const float* Wkg    = (const float*)d_in[3];
    const float* Wv     = (const float*)d_in[4];
    const float* Wg     = (const float*)d_in[5];
    const float* bg     = (const float*)d_in[6];
    const float* Wout   = (const float*)d_in[7];
    const float* aug    = (const float*)d_in[8];

    char* ws = (char*)d_ws;
    u16*   xb    = (u16*)  (ws + 0);            // 134217728 B (also PRE later)
    u16*   Wcat  = (u16*)  (ws + 134217728);    //   6291456
    u16*   WoutT = (u16*)  (ws + 140509184);    //   2097152
    u16*   qb    = (u16*)  (ws + 142606336);    //  67108864
    u16*   gkb   = (u16*)  (ws + 209715200);    //  67108864
    u16*   kbuf  = (u16*)  (ws + 276824064);    //  67108864
    u16*   sgb   = (u16*)  (ws + 343932928);    // 134217728
    float* Mbuf  = (float*)(ws + 478150656);    // 134217728
    float* eGC   = (float*)(ws + 612368384);    //   2097152
    float* Sb    = (float*)(ws + 614465536);    // 134217728 (optional)
    const size_t REQ_FULL = 748683264ull;
    int aliased = (ws_size < REQ_FULL) ? 1 : 0;
    float* Sbuf = aliased ? Mbuf : Sb;

    float* out = (float*)d_out;
    float* state_out = out + 67108864;
    u16* vb = (u16*)d_out;  // v (f16) lives in out region until GEMM2 overwrites it

    k_conv_silu<<<dim3(65536), dim3(256), 0, stream>>>(x, conv_w, xb);
    k_packW<<<dim3(16384), dim3(256), 0, stream>>>(Wq, Wkg, Wv, Wg, Wout, Wcat, WoutT);
    k_gemm_bt<1><<<dim3(6144), dim3(256), 0, stream>>>(xb, Wcat, 24,
                                                       qb, gkb, kbuf, vb, sgb, bg, nullptr);
    k_pass1<<<dim3(16384), dim3(64), 0, stream>>>(gkb, kbuf, vb, Mbuf, eGC);
    k_pass2<<<dim3(128), dim3(64), 0, stream>>>(Mbuf, Sbuf, eGC, state_out, aliased);
    k_pass3<<<dim3(16384), dim3(64), 0, stream>>>(qb, gkb, kbuf, vb, sgb, Sbuf, aug, xb /*PRE*/);
    k_gemm_bt<2><<<dim3(2048), dim3(256), 0, stream>>>(xb, WoutT, 8,
                                                       nullptr, nullptr, nullptr, nullptr, nullptr, nullptr, out);
}

// Round 16
// 1705.737 us; speedup vs baseline: 2.5885x; 1.0675x over previous
//
#include <hip/hip_runtime.h>
#include <stdint.h>

typedef __attribute__((ext_vector_type(4))) float f32x4;
typedef _Float16 f16x8 __attribute__((ext_vector_type(8)));
typedef __attribute__((ext_vector_type(8))) unsigned short u16x8;
typedef __attribute__((ext_vector_type(2))) unsigned int u32x2;
typedef unsigned short u16;
typedef unsigned int u32;

#define LSEQ 8192
#define BB 8
#define DD 1024
#define MM 65536      // B*L
#define NCH 128       // chunks per sequence (L/64)

__device__ __forceinline__ u16 f2h(float f) {
    _Float16 h = (_Float16)f;
    return *(u16*)&h;
}
__device__ __forceinline__ float h2f(u16 u) {
    _Float16 h = *(_Float16*)&u;
    return (float)h;
}

__device__ __forceinline__ void gload_lds16(const void* g, void* l) {
    __builtin_amdgcn_global_load_lds(
        (const __attribute__((address_space(1))) u32*)g,
        (__attribute__((address_space(3))) u32*)l, 16, 0, 0);
}

// ---------------- conv + silu + transpose -> xb f16 [B*L][D] ----------------
__global__ __launch_bounds__(256) void k_conv_silu(const float* __restrict__ x,
                                                   const float* __restrict__ w,
                                                   u16* __restrict__ xb) {
    int m = blockIdx.x;              // m = b*L + l
    int b = m >> 13, l = m & 8191;
    int d0 = threadIdx.x * 4;
    f32x4 wv[4];
#pragma unroll
    for (int j = 0; j < 4; j++) wv[j] = *(const f32x4*)&w[(d0 + j) * 4];
    float acc[4] = {0.f, 0.f, 0.f, 0.f};
#pragma unroll
    for (int kk = 0; kk < 4; kk++) {
        int lp = l - 3 + kk;
        if (lp >= 0) {
            f32x4 xv = *(const f32x4*)&x[((size_t)(lp * BB + b)) * DD + d0];
#pragma unroll
            for (int j = 0; j < 4; j++) acc[j] += xv[j] * wv[j][kk];
        }
    }
    u16 o[4];
#pragma unroll
    for (int j = 0; j < 4; j++) {
        float a = acc[j];
        o[j] = f2h(a / (1.f + __expf(-a)));
    }
    u32x2 pk;
    pk.x = (u32)o[0] | ((u32)o[1] << 16);
    pk.y = (u32)o[2] | ((u32)o[3] << 16);
    *(u32x2*)&xb[(size_t)m * DD + d0] = pk;
}

// ---------------- pack weights into B^T f16 layouts ----------------
__global__ __launch_bounds__(256) void k_packW(const float* __restrict__ Wq,
                                               const float* __restrict__ Wkg,
                                               const float* __restrict__ Wv,
                                               const float* __restrict__ Wg,
                                               const float* __restrict__ Wout,
                                               u16* __restrict__ Wcat,
                                               u16* __restrict__ WoutT) {
    int idx = blockIdx.x * 256 + threadIdx.x;
    const int T1 = 3072 * 1024;
    if (idx < T1) {
        int n = idx >> 10, kk = idx & 1023;
        float v;
        if (n < 512)        v = Wq [kk * 512 + n];
        else if (n < 1024)  v = Wkg[kk * 512 + (n - 512)];
        else if (n < 2048)  v = Wv [kk * 1024 + (n - 1024)];
        else                v = Wg [kk * 1024 + (n - 2048)];
        Wcat[idx] = f2h(v);
    } else {
        int j = idx - T1;
        if (j < 1024 * 1024) {
            int n = j >> 10, kk = j & 1023;
            WoutT[j] = f2h(Wout[kk * 1024 + n]);
        }
    }
}

// per-fragment epilogue (4 rows x 1 col-group of 16 handled by caller's lr)
template <int MODE>
__device__ __forceinline__ void epi_frag(f32x4 v, int grow0, int gcol,
                                         u16* __restrict__ qo, u16* __restrict__ gko,
                                         u16* __restrict__ ko, u16* __restrict__ vo,
                                         u16* __restrict__ sgo, const float* __restrict__ bg,
                                         float* __restrict__ out) {
#pragma unroll
    for (int rr = 0; rr < 4; rr++) {
        int grow = grow0 + rr;
        float val = v[rr];
        if (MODE == 1) {
            if (gcol < 512) {
                qo[(size_t)grow * 512 + gcol] = f2h(val);
            } else if (gcol < 1024) {
                float ls = fminf(val, 0.f) - log1pf(__expf(-fabsf(val)));
                float gkv = ls * 0.0625f;
                gko[(size_t)grow * 512 + (gcol - 512)] = f2h(gkv);
                ko [(size_t)grow * 512 + (gcol - 512)] = f2h(-expm1f(gkv));
            } else if (gcol < 2048) {
                vo[(size_t)grow * 1024 + (gcol - 1024)] = f2h(val);
            } else {
                float gg = val + bg[gcol - 2048];
                sgo[(size_t)grow * 1024 + (gcol - 2048)] = f2h(gg / (1.f + __expf(-gg)));
            }
        } else {
            int l = grow & 8191, b = grow >> 13;
            out[((size_t)(l * BB + b)) * DD + gcol] = val;
        }
    }
}

// ---------------- f16 GEMM, C = A[M][K] * Bt[N][K]^T, 256x64 tile, BK=32 ----------------
// R15 post-mortem: NaN was a one-line LDS bug — B-staging base was Sm+32768
// (stale from R13's 32KB-A layout) while reads expect B at byte 16384.
// Layout: buf = 20KB (A 0..16383 | B 16384..20479), buf1 at +20480.
// Geometry (untested R15 theory): wave-tile 128x32 (acc 64 regs), 4 waves,
// tile 256x64, LDS 40KB, launch_bounds(256,3) -> 3 blocks/CU = 3 waves/SIMD.
template <int MODE>
__global__ __launch_bounds__(256, 3) void k_gemm_bt(
    const u16* __restrict__ A, const u16* __restrict__ Bt, int nt_tiles,
    u16* __restrict__ qo, u16* __restrict__ gko, u16* __restrict__ ko,
    u16* __restrict__ vo, u16* __restrict__ sgo, const float* __restrict__ bg,
    float* __restrict__ out) {
    const int K = 1024;
    __shared__ __align__(16) u16 Sm[20480];   // 40 KB: 2 bufs x (A 16KB | B 4KB)
    int tid = threadIdx.x;
    int w = tid >> 6, lane = tid & 63;
    int wm = w >> 1, wn = w & 1;
    int lr = lane & 15, lk = lane >> 4;

    // XCD-aware 2D-blocked tile mapping
    int xcd = blockIdx.x & 7;
    int cidx = blockIdx.x >> 3;
    int grpsz = nt_tiles * 4;
    int grp = cidx / grpsz;
    int r = cidx - grp * grpsz;
    int ntile = r >> 2;
    int mts_per_chunk = (gridDim.x >> 3) / nt_tiles;   // 32
    int mtile = xcd * mts_per_chunk + grp * 4 + (r & 3);
    int m0 = mtile << 8, n0 = ntile << 6;

#define DECL_ACC(MT) f32x4 a##MT##_0 = {0.f,0.f,0.f,0.f}, a##MT##_1 = {0.f,0.f,0.f,0.f};
    DECL_ACC(0) DECL_ACC(1) DECL_ACC(2) DECL_ACC(3)
    DECL_ACC(4) DECL_ACC(5) DECL_ACC(6) DECL_ACC(7)
#undef DECL_ACC

    // staging: thread -> row tid>>2, slot tid&3; src slot pre-XOR'd with row&3
    int row = tid >> 2;
    int sslot = (tid & 3) ^ (row & 3);
    const u16* gA = A + (size_t)(m0 + row) * K + sslot * 8;
    const u16* gB = Bt + (size_t)(n0 + row) * K + sslot * 8;   // rows 0..63
    char* lA = (char*)Sm + w * 1024;            // HW adds lane*16
    char* lB = (char*)Sm + 16384 + w * 1024;    // B region base = byte 16384

// 5 gloads: A rows +0/+64/+128/+192 (4 x 4KB), B rows 0..63 (1 x 4KB)
#define STAGE(TT, OB) { \
    int k1 = (TT) << 5; \
    gload_lds16(gA + k1, lA + (OB)); \
    gload_lds16(gA + (size_t)64 * K + k1, lA + (OB) + 4096); \
    gload_lds16(gA + (size_t)128 * K + k1, lA + (OB) + 8192); \
    gload_lds16(gA + (size_t)192 * K + k1, lA + (OB) + 12288); \
    gload_lds16(gB + k1, lB + (OB)); }

#define MFMA_ROW(MT) { \
    f16x8 av = *(const f16x8*)&As[(wm * 128 + MT * 16 + lr) * 32 + acsl]; \
    a##MT##_0 = __builtin_amdgcn_mfma_f32_16x16x32_f16(av, b0, a##MT##_0, 0, 0, 0); \
    a##MT##_1 = __builtin_amdgcn_mfma_f32_16x16x32_f16(av, b1, a##MT##_1, 0, 0, 0); }

#define COMPUTE() { \
    int acsl = (lk ^ (lr & 3)) * 8; \
    f16x8 b0 = *(const f16x8*)&Bs[(wn * 32 +  0 + lr) * 32 + acsl]; \
    f16x8 b1 = *(const f16x8*)&Bs[(wn * 32 + 16 + lr) * 32 + acsl]; \
    __builtin_amdgcn_s_setprio(1); \
    MFMA_ROW(0) MFMA_ROW(1) MFMA_ROW(2) MFMA_ROW(3) \
    MFMA_ROW(4) MFMA_ROW(5) MFMA_ROW(6) MFMA_ROW(7) \
    __builtin_amdgcn_s_setprio(0); }

    // prologue: stage K-tiles 0 and 1 (10 loads in flight per thread)
    STAGE(0, 0)
    STAGE(1, 20480)

    for (int t = 0; t < 31; ++t) {
        // wait own stage(t) loads only; stage(t+1)'s 5 stay in flight
        asm volatile("s_waitcnt vmcnt(5)" ::: "memory");
        __builtin_amdgcn_sched_barrier(0);
        __builtin_amdgcn_s_barrier();   // all waves' tile-t writes landed
        {
            const u16* As = Sm + (t & 1) * 10240;
            const u16* Bs = As + 8192;
            COMPUTE()
        }
        __builtin_amdgcn_s_barrier();   // buf(t&1) fully consumed
        __builtin_amdgcn_sched_barrier(0);
        if (t < 30) {
            STAGE(t + 2, (t & 1) * 20480)
        }
    }
    // tile 31 (buf 1): everything must be in
    asm volatile("s_waitcnt vmcnt(0)" ::: "memory");
    __builtin_amdgcn_sched_barrier(0);
    __builtin_amdgcn_s_barrier();
    {
        const u16* As = Sm + 10240;
        const u16* Bs = As + 8192;
        COMPUTE()
    }
#undef COMPUTE
#undef MFMA_ROW
#undef STAGE

#define EPI_ROW(MT) { \
    int gr0 = m0 + wm * 128 + MT * 16 + lk * 4; \
    epi_frag<MODE>(a##MT##_0, gr0, n0 + wn * 32 +  0 + lr, qo, gko, ko, vo, sgo, bg, out); \
    epi_frag<MODE>(a##MT##_1, gr0, n0 + wn * 32 + 16 + lr, qo, gko, ko, vo, sgo, bg, out); }
    EPI_ROW(0) EPI_ROW(1) EPI_ROW(2) EPI_ROW(3)
    EPI_ROW(4) EPI_ROW(5) EPI_ROW(6) EPI_ROW(7)
#undef EPI_ROW
}

// ---------------- pass1: per-chunk increment M_c = sum_s k_s e^{G_C - G_s} v_s^T ----------------
__global__ __launch_bounds__(64) void k_pass1(const u16* __restrict__ gkb,
                                              const u16* __restrict__ kb,
                                              const u16* __restrict__ vb,
                                              float* __restrict__ Mo,
                                              float* __restrict__ eGC) {
    __shared__ __align__(16) float kkT[64 * 32];  // [t][i] fp32
    int bhc = blockIdx.x;
    int c = bhc & 127, bh = bhc >> 7;
    int h = bh & 15, b = bh >> 4;
    int m0 = b * LSEQ + c * 64;
    int lane = threadIdx.x;
    if (lane < 32) {
        int i = lane;
        size_t base = (size_t)m0 * 512 + h * 32 + i;
        float G = 0.f;
        for (int t = 0; t < 64; t++) {
            G += h2f(gkb[base + (size_t)t * 512]);
            G = fmaxf(G, -60.f);
            kkT[t * 32 + i] = h2f(kb[base + (size_t)t * 512]) * __expf(-G);
        }
        eGC[bhc * 32 + i] = __expf(G);
    }
    __syncthreads();
    float Ma[32];
#pragma unroll
    for (int i = 0; i < 32; i++) Ma[i] = 0.f;
    size_t vbase = (size_t)m0 * 1024 + h * 64 + lane;
    for (int t = 0; t < 64; t++) {
        float vj = h2f(vb[vbase + (size_t)t * 1024]);
#pragma unroll
        for (int i4 = 0; i4 < 32; i4 += 4) {
            f32x4 kk4 = *(const f32x4*)&kkT[t * 32 + i4];
            Ma[i4 + 0] += kk4[0] * vj;
            Ma[i4 + 1] += kk4[1] * vj;
            Ma[i4 + 2] += kk4[2] * vj;
            Ma[i4 + 3] += kk4[3] * vj;
        }
    }
    size_t mb = (size_t)bhc * 2048 + lane;
#pragma unroll
    for (int i = 0; i < 32; i++) Mo[mb + i * 64] = Ma[i];
}

// ---------------- pass2: chunk-level recurrence, i-rows split across 4 blocks ----------------
__global__ __launch_bounds__(64) void k_pass2(float* Mbuf, float* Sbuf,
                                              const float* __restrict__ eGC,
                                              float* __restrict__ state_out, int aliased) {
    int blk = blockIdx.x;
    int bh = blk >> 2, iq = blk & 3;
    int i0 = iq * 8;
    int j = threadIdx.x;
    float S[8];
#pragma unroll
    for (int i = 0; i < 8; i++) S[i] = 0.f;
    for (int c = 0; c < NCH; c++) {
        size_t base = ((size_t)bh * NCH + c) * 2048;
        float mv[8], ev[8];
#pragma unroll
        for (int i = 0; i < 8; i++) mv[i] = Mbuf[base + (i0 + i) * 64 + j];
#pragma unroll
        for (int i = 0; i < 8; i++) ev[i] = eGC[(bh * NCH + c) * 32 + i0 + i];
        if (aliased) { asm volatile("s_waitcnt vmcnt(0)" ::: "memory"); }
#pragma unroll
        for (int i = 0; i < 8; i++) Sbuf[base + (i0 + i) * 64 + j] = S[i];  // chunk-START state
#pragma unroll
        for (int i = 0; i < 8; i++) S[i] = (S[i] + mv[i]) * ev[i];
    }
    size_t so = (size_t)bh * 2048 + j;
#pragma unroll
    for (int i = 0; i < 8; i++) state_out[so + (i0 + i) * 64] = S[i];
}

// ---------------- pass3: intra-chunk outputs + aug + groupnorm + silu-gate ----------------
// (R14 structure: f16 qqT/kkT, full-wave aug, 4-way o-split — verified -300us)
__global__ __launch_bounds__(64) void k_pass3(const u16* __restrict__ qb,
                                              const u16* __restrict__ gkb,
                                              const u16* __restrict__ kb,
                                              const u16* __restrict__ vb,
                                              const u16* __restrict__ sgb,
                                              const float* __restrict__ Sbuf,
                                              const float* __restrict__ aug,
                                              u16* __restrict__ PRE) {
    __shared__ __align__(16) u16 qqT[64 * 32];  // [t][i] f16
    __shared__ __align__(16) u16 kkT[64 * 32];
    __shared__ float awl[64];
    int bhc = blockIdx.x;
    int c = bhc & 127, bh = bhc >> 7;
    int h = bh & 15, b = bh >> 4;
    int m0 = b * LSEQ + c * 64;
    int lane = threadIdx.x;
    const float scale = 0.17677669529663689f;  // 1/sqrt(32)
    // phase 1a: serial-G transform (32 lanes; G prefix is inherently serial in t)
    if (lane < 32) {
        int i = lane;
        size_t base = (size_t)m0 * 512 + h * 32 + i;
        float G = 0.f;
        for (int t = 0; t < 64; t++) {
            float gkv = h2f(gkb[base + (size_t)t * 512]);
            float qv  = h2f(qb [base + (size_t)t * 512]);
            float kv  = h2f(kb [base + (size_t)t * 512]);
            G += gkv;
            G = fmaxf(G, -60.f);
            qqT[t * 32 + i] = f2h(qv * __expf(G) * scale);
            kkT[t * 32 + i] = f2h(kv * __expf(-G));
        }
    }
    // phase 1b: aug weights, all 64 lanes, 2 t's per iteration
    {
        int i = lane & 31;
        int th = (lane >> 5) << 5;     // 0 or 32
        float augi = aug[h * 32 + i];
        size_t base2 = (size_t)m0 * 512 + h * 32 + i;
        for (int tt = 0; tt < 32; tt++) {
            int t = tt + th;
            float qv = h2f(qb[base2 + (size_t)t * 512]);
            float kv = h2f(kb[base2 + (size_t)t * 512]);
            float p = qv * kv * augi;
            p += __shfl_xor(p, 1);
            p += __shfl_xor(p, 2);
            p += __shfl_xor(p, 4);
            p += __shfl_xor(p, 8);
            p += __shfl_xor(p, 16);
            if (i == 0) awl[t] = p;
        }
    }
    __syncthreads();
    float T[32];
    size_t sb = (size_t)bhc * 2048 + lane;
#pragma unroll
    for (int i = 0; i < 32; i++) T[i] = Sbuf[sb + i * 64];
    size_t vbase = (size_t)m0 * 1024 + h * 64 + lane;
    for (int t = 0; t < 64; t++) {
        float vj  = h2f(vb [vbase + (size_t)t * 1024]);
        float sgj = h2f(sgb[vbase + (size_t)t * 1024]);
        float aw = awl[t];
        float o0 = 0.f, o1 = 0.f, o2 = 0.f, o3 = 0.f;
        u16x8 kk8a = *(const u16x8*)&kkT[t * 32 + 0];
        u16x8 qq8a = *(const u16x8*)&qqT[t * 32 + 0];
        u16x8 kk8b = *(const u16x8*)&kkT[t * 32 + 8];
        u16x8 qq8b = *(const u16x8*)&qqT[t * 32 + 8];
        u16x8 kk8c = *(const u16x8*)&kkT[t * 32 + 16];
        u16x8 qq8c = *(const u16x8*)&qqT[t * 32 + 16];
        u16x8 kk8d = *(const u16x8*)&kkT[t * 32 + 24];
        u16x8 qq8d = *(const u16x8*)&qqT[t * 32 + 24];
#pragma unroll
        for (int e = 0; e < 8; e++) {
            T[e]      += h2f(kk8a[e]) * vj;  o0 += h2f(qq8a[e]) * T[e];
            T[8 + e]  += h2f(kk8b[e]) * vj;  o1 += h2f(qq8b[e]) * T[8 + e];
            T[16 + e] += h2f(kk8c[e]) * vj;  o2 += h2f(qq8c[e]) * T[16 + e];
            T[24 + e] += h2f(kk8d[e]) * vj;  o3 += h2f(qq8d[e]) * T[24 + e];
        }
        float o = (o0 + o1) + (o2 + o3);
        o += 1.f / (1.f + __expf(-aw * vj));       // + sigmoid(aug_w * v)
        // group norm over dv=64 (all 64 lanes)
        float s1 = o, s2 = o * o;
#pragma unroll
        for (int msk = 1; msk < 64; msk <<= 1) {
            s1 += __shfl_xor(s1, msk);
            s2 += __shfl_xor(s2, msk);
        }
        float mu = s1 * 0.015625f;
        float var = s2 * 0.015625f - mu * mu;
        float on = (o - mu) * rsqrtf(fmaxf(var, 0.f) + 1e-5f);
        PRE[vbase + (size_t)t * 1024] = f2h(on * sgj);
    }
}

// ---------------- host launch ----------------
extern "C" void kernel_launch(void* const* d_in, const int* in_sizes, int n_in,
                              void* d_out, int out_size, void* d_ws, size_t ws_size,
                              hipStream_t stream) {
    (void)in_sizes; (void)n_in; (void)out_size;
    const float* x      = (const float*)d_in[0];
    const float* conv_w = (const float*)d_in[1];
    const float* Wq     = (const float*)d_in[2];
    const float* Wkg    = (const float*)d_in[3];
    const float* Wv     = (const float*)d_in[4];
    const float* Wg     = (const float*)d_in[5];
    const float* bg     = (const float*)d_in[6];
    const float* Wout   = (const float*)d_in[7];
    const float* aug    = (const float*)d_in[8];

    char* ws = (char*)d_ws;
    u16*   xb    = (u16*)  (ws + 0);            // 134217728 B (also PRE later)
    u16*   Wcat  = (u16*)  (ws + 134217728);    //   6291456
    u16*   WoutT = (u16*)  (ws + 140509184);    //   2097152
    u16*   qb    = (u16*)  (ws + 142606336);    //  67108864
    u16*   gkb   = (u16*)  (ws + 209715200);    //  67108864
    u16*   kbuf  = (u16*)  (ws + 276824064);    //  67108864
    u16*   sgb   = (u16*)  (ws + 343932928);    // 134217728
    float* Mbuf  = (float*)(ws + 478150656);    // 134217728
    float* eGC   = (float*)(ws + 612368384);    //   2097152
    float* Sb    = (float*)(ws + 614465536);    // 134217728 (optional)
    const size_t REQ_FULL = 748683264ull;
    int aliased = (ws_size < REQ_FULL) ? 1 : 0;
    float* Sbuf = aliased ? Mbuf : Sb;

    float* out = (float*)d_out;
    float* state_out = out + 67108864;
    u16* vb = (u16*)d_out;  // v (f16) lives in out region until GEMM2 overwrites it

    k_conv_silu<<<dim3(65536), dim3(256), 0, stream>>>(x, conv_w, xb);
    k_packW<<<dim3(16384), dim3(256), 0, stream>>>(Wq, Wkg, Wv, Wg, Wout, Wcat, WoutT);
    k_gemm_bt<1><<<dim3(12288), dim3(256), 0, stream>>>(xb, Wcat, 48,
                                                        qb, gkb, kbuf, vb, sgb, bg, nullptr);
    k_pass1<<<dim3(16384), dim3(64), 0, stream>>>(gkb, kbuf, vb, Mbuf, eGC);
    k_pass2<<<dim3(512), dim3(64), 0, stream>>>(Mbuf, Sbuf, eGC, state_out, aliased);
    k_pass3<<<dim3(16384), dim3(64), 0, stream>>>(qb, gkb, kbuf, vb, sgb, Sbuf, aug, xb /*PRE*/);
    k_gemm_bt<2><<<dim3(4096), dim3(256), 0, stream>>>(xb, WoutT, 16,
                                                       nullptr, nullptr, nullptr, nullptr, nullptr, nullptr, out);
}